// Round 5
// baseline (331.579 us; speedup 1.0000x reference)
//
#include <hip/hip_runtime.h>

#define NN 50000
#define EE 600000
#define INF 256
#define HF 128

typedef __attribute__((ext_vector_type(8))) short short8;
typedef __attribute__((ext_vector_type(4))) float floatx4;

// ---------------- bf16 helpers ----------------
__device__ __forceinline__ unsigned short f32_to_bf16_rne(float x) {
    unsigned int u = __float_as_uint(x);
    unsigned int r = (u + 0x7FFFu + ((u >> 16) & 1u)) >> 16;
    return (unsigned short)r;
}
__device__ __forceinline__ float bf16_to_f32(unsigned short h) {
    return __uint_as_float(((unsigned int)h) << 16);
}
__device__ __forceinline__ float bf16lo_u32(unsigned int u) {
    return __uint_as_float(u << 16);
}
__device__ __forceinline__ float bf16hi_u32(unsigned int u) {
    return __uint_as_float(u & 0xFFFF0000u);
}
// 8 f32 -> hi/lo bf16 fragment pair
__device__ __forceinline__ void cvt_hilo8(float4 v0, float4 v1, short8& hs, short8& ls) {
    float x[8] = {v0.x, v0.y, v0.z, v0.w, v1.x, v1.y, v1.z, v1.w};
    union { short8 s; unsigned short u[8]; } H, L;
#pragma unroll
    for (int k = 0; k < 8; ++k) {
        unsigned short hi = f32_to_bf16_rne(x[k]);
        H.u[k] = hi;
        L.u[k] = f32_to_bf16_rne(x[k] - bf16_to_f32(hi));
    }
    hs = H.s;
    ls = L.s;
}

// ---------------- degree counting ----------------
__global__ void count_deg(const int* __restrict__ row, int* __restrict__ cnt, int E) {
    int e = blockIdx.x * blockDim.x + threadIdx.x;
    if (e < E) atomicAdd(&cnt[row[e]], 1);
}

// ---------------- 3-phase exclusive scan (for CSR row_start) ----------------
__global__ void scan_phase1(const int* __restrict__ cnt, int* __restrict__ bsum, int n) {
    __shared__ int sdata[256];
    int t = threadIdx.x;
    int i = blockIdx.x * 256 + t;
    sdata[t] = (i < n) ? cnt[i] : 0;
    __syncthreads();
    for (int s = 128; s > 0; s >>= 1) {
        if (t < s) sdata[t] += sdata[t + s];
        __syncthreads();
    }
    if (t == 0) bsum[blockIdx.x] = sdata[0];
}

__global__ void scan_phase2(int* __restrict__ bsum, int nb) {
    __shared__ int sdata[256];
    int t = threadIdx.x;
    int v = (t < nb) ? bsum[t] : 0;
    sdata[t] = v;
    __syncthreads();
    for (int s = 1; s < 256; s <<= 1) {
        int add = (t >= s) ? sdata[t - s] : 0;
        __syncthreads();
        sdata[t] += add;
        __syncthreads();
    }
    if (t < nb) bsum[t] = sdata[t] - v;   // exclusive
}

// scan_phase3 + finalize_deg folded
__global__ void scan_phase3(const int* __restrict__ cnt, const int* __restrict__ bsum,
                            int* __restrict__ row_start, int* __restrict__ fill_pos,
                            float* __restrict__ deg_inv, float* __restrict__ dis,
                            int n, int E) {
    __shared__ int sdata[256];
    int t = threadIdx.x;
    int i = blockIdx.x * 256 + t;
    int v = (i < n) ? cnt[i] : 0;
    sdata[t] = v;
    __syncthreads();
    for (int s = 1; s < 256; s <<= 1) {
        int add = (t >= s) ? sdata[t - s] : 0;
        __syncthreads();
        sdata[t] += add;
        __syncthreads();
    }
    if (i < n) {
        int ex = bsum[blockIdx.x] + sdata[t] - v;
        row_start[i] = ex;
        fill_pos[i] = ex;
        float d = (float)(v + 1);
        deg_inv[i] = 1.0f / d;
        dis[i] = rsqrtf(d);
    }
    if (blockIdx.x == 0 && t == 0) row_start[n] = E;
}

// only csr_col now (4B/edge scatter; weights folded into pre-scaled hbf)
__global__ void fill_csr(const int* __restrict__ row, const int* __restrict__ col,
                         int* __restrict__ fill_pos, int* __restrict__ csr_col, int E) {
    int e = blockIdx.x * blockDim.x + threadIdx.x;
    if (e < E) {
        int r = row[e];
        int p = atomicAdd(&fill_pos[r], 1);
        csr_col[p] = col[e];
    }
}

// ---------------- prepack weights into MFMA B-fragment order (hi/lo bf16) --------------
// frag[((kc*8 + nt)*64 + lane)*8 + j] = W[nt*16 + (lane&15)][kc*32 + (lane>>4)*8 + j]
// lin: kc 0..7 (4096 chunks), conv: kc 0..3 (2048 chunks); one 8-elem chunk per thread.
__global__ void prepack_w(const float* __restrict__ lw, const float* __restrict__ cw,
                          unsigned short* __restrict__ flh, unsigned short* __restrict__ fll,
                          unsigned short* __restrict__ fch, unsigned short* __restrict__ fcl) {
    int idx = blockIdx.x * blockDim.x + threadIdx.x;
    const float* src;
    unsigned short *dh, *dl;
    int K, i;
    if (idx < 4096) {
        src = lw; dh = flh; dl = fll; K = INF; i = idx;
    } else if (idx < 6144) {
        src = cw; dh = fch; dl = fcl; K = HF; i = idx - 4096;
    } else return;
    int lane = i & 63;
    int nt = (i >> 6) & 7;
    int kc = i >> 9;
    int rw = nt * 16 + (lane & 15);
    int koff = kc * 32 + (lane >> 4) * 8;
    const float* p = &src[(size_t)rw * K + koff];
    float4 v0 = *reinterpret_cast<const float4*>(p);
    float4 v1 = *reinterpret_cast<const float4*>(p + 4);
    short8 hs, ls;
    cvt_hilo8(v0, v1, hs, ls);
    *reinterpret_cast<short8*>(&dh[(size_t)i * 8]) = hs;
    *reinterpret_cast<short8*>(&dl[(size_t)i * 8]) = ls;
}

// ---------------- LDS-free split-bf16 MFMA GEMM: C[M][128] = A[M][K] @ W[128][K]^T ------
// No __shared__, no barriers: A fragments loaded straight from global (layout matches
// MFMA A-operand), W fragments from prepacked fragment-order global arrays (L2-resident).
// TM=64/block (4 waves x 16 rows), grid 782.
// MODE 0 (lin):   A=f32, convert in regs. C = acc+bias -> f32; Cbf = bf16(dis*C).
// MODE 1 (conv+LN): A=packed hi/lo. v = acc+conv_b+relu(h+root)*deg_inv; x=v+h;
//                   LN; relu -> C (in-place h) f32; Cbf = bf16(dis*C).
// MODE 2 (conv+out): A packed. C = acc+conv_b+relu(h+root)*deg_inv.
template <int K, int MODE>
__global__ __launch_bounds__(256) void gemm_nolds(
    const float* __restrict__ Af,
    const unsigned short* __restrict__ Ahg, const unsigned short* __restrict__ Alg,
    const unsigned short* __restrict__ Wfh, const unsigned short* __restrict__ Wfl,
    const float* __restrict__ bias,
    float* __restrict__ C, unsigned short* __restrict__ Cbf,
    const float* __restrict__ h, const float* __restrict__ deg_inv,
    const float* __restrict__ dis, const float* __restrict__ root,
    const float* __restrict__ gamma, const float* __restrict__ beta,
    int M) {
    const int t = threadIdx.x;
    const int wave = t >> 6;
    const int lane = t & 63;
    const int lrow = lane & 15;
    const int quad = lane >> 4;
    const int bm = blockIdx.x * 64;
    int arow = bm + wave * 16 + lrow;
    if (arow >= M) arow = M - 1;   // clamp; stores are predicated

    floatx4 acc[8];
#pragma unroll
    for (int nt = 0; nt < 8; ++nt) acc[nt] = (floatx4){0.f, 0.f, 0.f, 0.f};

#pragma unroll 2
    for (int kc = 0; kc < K / 32; ++kc) {
        short8 afh, afl;
        if (MODE == 0) {
            const float* ap = &Af[(size_t)arow * K + kc * 32 + quad * 8];
            float4 a0 = *reinterpret_cast<const float4*>(ap);
            float4 a1 = *reinterpret_cast<const float4*>(ap + 4);
            cvt_hilo8(a0, a1, afh, afl);
        } else {
            size_t ao = (size_t)arow * K + kc * 32 + quad * 8;
            afh = *reinterpret_cast<const short8*>(&Ahg[ao]);
            afl = *reinterpret_cast<const short8*>(&Alg[ao]);
        }
        const unsigned short* wh = &Wfh[(size_t)kc * 4096 + lane * 8];
        const unsigned short* wl = &Wfl[(size_t)kc * 4096 + lane * 8];
#pragma unroll
        for (int nt = 0; nt < 8; ++nt) {
            short8 bfh = *reinterpret_cast<const short8*>(wh + nt * 512);
            short8 bfl = *reinterpret_cast<const short8*>(wl + nt * 512);
            acc[nt] = __builtin_amdgcn_mfma_f32_16x16x32_bf16(afh, bfh, acc[nt], 0, 0, 0);
            acc[nt] = __builtin_amdgcn_mfma_f32_16x16x32_bf16(afl, bfh, acc[nt], 0, 0, 0);
            acc[nt] = __builtin_amdgcn_mfma_f32_16x16x32_bf16(afh, bfl, acc[nt], 0, 0, 0);
        }
    }

    // per-column constants (col = nt*16 + lrow, fixed across rows)
    float cb[8], rt[8], gm[8], bt[8];
#pragma unroll
    for (int nt = 0; nt < 8; ++nt) {
        int colh = nt * 16 + lrow;
        cb[nt] = bias[colh];
        if (MODE >= 1) rt[nt] = root[colh];
        if (MODE == 1) { gm[nt] = gamma[colh]; bt[nt] = beta[colh]; }
    }

    // epilogue: C/D layout col=lane&15, row=quad*4+r
#pragma unroll
    for (int r = 0; r < 4; ++r) {
        int grow = bm + wave * 16 + quad * 4 + r;
        bool ok = (grow < M);
        int gr = ok ? grow : M - 1;
        float x[8];
        if (MODE == 0) {
#pragma unroll
            for (int nt = 0; nt < 8; ++nt) x[nt] = acc[nt][r] + cb[nt];
        } else {
            float di = deg_inv[gr];
            float hv[8];
#pragma unroll
            for (int nt = 0; nt < 8; ++nt) hv[nt] = h[(size_t)gr * HF + nt * 16 + lrow];
#pragma unroll
            for (int nt = 0; nt < 8; ++nt) {
                float v = acc[nt][r] + cb[nt] + fmaxf(hv[nt] + rt[nt], 0.f) * di;
                x[nt] = (MODE == 1) ? v + hv[nt] : v;   // MODE1: residual with ori=h
            }
        }
        if (MODE == 1) {
            float s = 0.f;
#pragma unroll
            for (int nt = 0; nt < 8; ++nt) s += x[nt];
#pragma unroll
            for (int m = 1; m < 16; m <<= 1) s += __shfl_xor(s, m, 64);
            float mu = s * (1.0f / HF);
            float var = 0.f;
#pragma unroll
            for (int nt = 0; nt < 8; ++nt) { float d = x[nt] - mu; var += d * d; }
#pragma unroll
            for (int m = 1; m < 16; m <<= 1) var += __shfl_xor(var, m, 64);
            float rs = rsqrtf(var * (1.0f / HF) + 1e-5f);
            float ds = dis[gr];
            if (ok) {
#pragma unroll
                for (int nt = 0; nt < 8; ++nt) {
                    int colh = nt * 16 + lrow;
                    float y = fmaxf((x[nt] - mu) * rs * gm[nt] + bt[nt], 0.f);
                    C[(size_t)grow * HF + colh] = y;
                    Cbf[(size_t)grow * HF + colh] = f32_to_bf16_rne(ds * y);
                }
            }
        } else if (MODE == 0) {
            if (ok) {
                float ds = dis[grow];
#pragma unroll
                for (int nt = 0; nt < 8; ++nt) {
                    int colh = nt * 16 + lrow;
                    C[(size_t)grow * HF + colh] = x[nt];
                    Cbf[(size_t)grow * HF + colh] = f32_to_bf16_rne(ds * x[nt]);
                }
            }
        } else {
            if (ok) {
#pragma unroll
                for (int nt = 0; nt < 8; ++nt)
                    C[(size_t)grow * HF + nt * 16 + lrow] = x[nt];
            }
        }
    }
}

// ---------------- aggregate: agg = dis[t]*sum_e hbf[c] + deg_inv[t]*h[t] ----------------
// hbf is pre-scaled by dis[c]; one wave per node, quarter-wave per edge; bf16 hi/lo out.
__global__ void aggregate(const int* __restrict__ row_start, const int* __restrict__ csr_col,
                          const float* __restrict__ dis, const float* __restrict__ deg_inv,
                          const float* __restrict__ h, const unsigned short* __restrict__ hbf,
                          unsigned short* __restrict__ agg_hi, unsigned short* __restrict__ agg_lo,
                          int n) {
    int wid = (blockIdx.x * blockDim.x + threadIdx.x) >> 6;
    int lane = threadIdx.x & 63;
    if (wid >= n) return;
    int q = lane >> 4;
    int l16 = lane & 15;
    int s = row_start[wid];
    int e = row_start[wid + 1];
    float a0 = 0.f, a1 = 0.f, a2 = 0.f, a3 = 0.f, a4 = 0.f, a5 = 0.f, a6 = 0.f, a7 = 0.f;
    for (int j = s + q; j < e; j += 4) {
        int c = csr_col[j];
        uint4 hv = *reinterpret_cast<const uint4*>(&hbf[(size_t)c * HF + l16 * 8]);
        a0 += bf16lo_u32(hv.x);
        a1 += bf16hi_u32(hv.x);
        a2 += bf16lo_u32(hv.y);
        a3 += bf16hi_u32(hv.y);
        a4 += bf16lo_u32(hv.z);
        a5 += bf16hi_u32(hv.z);
        a6 += bf16lo_u32(hv.w);
        a7 += bf16hi_u32(hv.w);
    }
    // reduce the 4 quarters (lanes with equal l16)
#pragma unroll
    for (int m = 16; m < 64; m <<= 1) {
        a0 += __shfl_xor(a0, m, 64);
        a1 += __shfl_xor(a1, m, 64);
        a2 += __shfl_xor(a2, m, 64);
        a3 += __shfl_xor(a3, m, 64);
        a4 += __shfl_xor(a4, m, 64);
        a5 += __shfl_xor(a5, m, 64);
        a6 += __shfl_xor(a6, m, 64);
        a7 += __shfl_xor(a7, m, 64);
    }
    if (q == 0) {
        float dn = dis[wid];
        float di = deg_inv[wid];
        float4 hA = *reinterpret_cast<const float4*>(&h[(size_t)wid * HF + l16 * 8]);
        float4 hB = *reinterpret_cast<const float4*>(&h[(size_t)wid * HF + l16 * 8 + 4]);
        float o[8];
        o[0] = fmaf(dn, a0, di * hA.x);
        o[1] = fmaf(dn, a1, di * hA.y);
        o[2] = fmaf(dn, a2, di * hA.z);
        o[3] = fmaf(dn, a3, di * hA.w);
        o[4] = fmaf(dn, a4, di * hB.x);
        o[5] = fmaf(dn, a5, di * hB.y);
        o[6] = fmaf(dn, a6, di * hB.z);
        o[7] = fmaf(dn, a7, di * hB.w);
        unsigned short hi[8], lo[8];
#pragma unroll
        for (int k = 0; k < 8; ++k) {
            hi[k] = f32_to_bf16_rne(o[k]);
            lo[k] = f32_to_bf16_rne(o[k] - bf16_to_f32(hi[k]));
        }
        uint4 hp, lp;
        hp.x = (unsigned)hi[0] | ((unsigned)hi[1] << 16);
        hp.y = (unsigned)hi[2] | ((unsigned)hi[3] << 16);
        hp.z = (unsigned)hi[4] | ((unsigned)hi[5] << 16);
        hp.w = (unsigned)hi[6] | ((unsigned)hi[7] << 16);
        lp.x = (unsigned)lo[0] | ((unsigned)lo[1] << 16);
        lp.y = (unsigned)lo[2] | ((unsigned)lo[3] << 16);
        lp.z = (unsigned)lo[4] | ((unsigned)lo[5] << 16);
        lp.w = (unsigned)lo[6] | ((unsigned)lo[7] << 16);
        *reinterpret_cast<uint4*>(&agg_hi[(size_t)wid * HF + l16 * 8]) = hp;
        *reinterpret_cast<uint4*>(&agg_lo[(size_t)wid * HF + l16 * 8]) = lp;
    }
}

extern "C" void kernel_launch(void* const* d_in, const int* in_sizes, int n_in,
                              void* d_out, int out_size, void* d_ws, size_t ws_size,
                              hipStream_t stream) {
    const int N = NN, E = EE;
    const float* in_feat = (const float*)d_in[0];
    const int* row = (const int*)d_in[1];
    const int* col = (const int*)d_in[2];
    const float* lin_w = (const float*)d_in[3];
    const float* lin_b = (const float*)d_in[4];
    const float* conv_w = (const float*)d_in[5];
    const float* conv_b = (const float*)d_in[6];
    const float* root_emb = (const float*)d_in[7];
    const float* ln_gamma = (const float*)d_in[8];
    const float* ln_beta = (const float*)d_in[9];
    float* out = (float*)d_out;

    // workspace layout (4B units); all segments kept 16B-aligned
    float* ws = (float*)d_ws;
    size_t o = 0;
    float* deg_inv = ws + o; o += N;
    float* dis = ws + o; o += N;
    int* cnt = (int*)(ws + o); o += N;
    int* row_start = (int*)(ws + o); o += N + 4;
    int* fill_pos = (int*)(ws + o); o += N;
    int* bsum = (int*)(ws + o); o += 256;
    int* csr_col = (int*)(ws + o); o += E;
    o = (o + 3) & ~(size_t)3;
    unsigned short* flh = (unsigned short*)(ws + o); o += 16384;  // 32768 ushort
    unsigned short* fll = (unsigned short*)(ws + o); o += 16384;
    unsigned short* fch = (unsigned short*)(ws + o); o += 8192;   // 16384 ushort
    unsigned short* fcl = (unsigned short*)(ws + o); o += 8192;
    float* h0 = ws + o; o += (size_t)N * HF;
    unsigned short* hbf = (unsigned short*)(ws + o); o += (size_t)N * HF / 2;
    unsigned short* agg_hi = (unsigned short*)(ws + o); o += (size_t)N * HF / 2;
    unsigned short* agg_lo = (unsigned short*)(ws + o); o += (size_t)N * HF / 2;

    const int NB = (N + 255) / 256;

    hipMemsetAsync(cnt, 0, N * sizeof(int), stream);
    count_deg<<<(E + 255) / 256, 256, 0, stream>>>(row, cnt, E);
    scan_phase1<<<NB, 256, 0, stream>>>(cnt, bsum, N);
    scan_phase2<<<1, 256, 0, stream>>>(bsum, NB);
    scan_phase3<<<NB, 256, 0, stream>>>(cnt, bsum, row_start, fill_pos, deg_inv, dis, N, E);
    fill_csr<<<(E + 255) / 256, 256, 0, stream>>>(row, col, fill_pos, csr_col, E);
    prepack_w<<<24, 256, 0, stream>>>(lin_w, conv_w, flh, fll, fch, fcl);

    const int GB = (N + 63) / 64;
    const int WB = (N + 3) / 4;

    // h0 = in_feat @ lin_w.T + lin_b  (f32 + dis-scaled bf16 copy)
    gemm_nolds<INF, 0><<<GB, 256, 0, stream>>>(in_feat, nullptr, nullptr, flh, fll, lin_b,
                                               h0, hbf, nullptr, nullptr, dis, nullptr,
                                               nullptr, nullptr, N);

    // ---- prop step 0 (conv + fused residual/LN/ReLU epilogue -> h0 in-place) ----
    aggregate<<<WB, 256, 0, stream>>>(row_start, csr_col, dis, deg_inv, h0, hbf,
                                      agg_hi, agg_lo, N);
    gemm_nolds<HF, 1><<<GB, 256, 0, stream>>>(nullptr, agg_hi, agg_lo, fch, fcl, conv_b,
                                              h0, hbf, h0, deg_inv, dis, root_emb,
                                              ln_gamma + HF, ln_beta + HF, N);

    // ---- prop step 1 (conv + combine epilogue -> out) ----
    aggregate<<<WB, 256, 0, stream>>>(row_start, csr_col, dis, deg_inv, h0, hbf,
                                      agg_hi, agg_lo, N);
    gemm_nolds<HF, 2><<<GB, 256, 0, stream>>>(nullptr, agg_hi, agg_lo, fch, fcl, conv_b,
                                              out, nullptr, h0, deg_inv, dis, root_emb,
                                              nullptr, nullptr, N);
}

// Round 6
// 312.913 us; speedup vs baseline: 1.0597x; 1.0597x over previous
//
#include <hip/hip_runtime.h>

#define NN 50000
#define EE 600000
#define INF 256
#define HF 128

typedef __attribute__((ext_vector_type(8))) short short8;
typedef __attribute__((ext_vector_type(4))) float floatx4;

// ---------------- bf16 helpers ----------------
__device__ __forceinline__ unsigned short f32_to_bf16_rne(float x) {
    unsigned int u = __float_as_uint(x);
    unsigned int r = (u + 0x7FFFu + ((u >> 16) & 1u)) >> 16;
    return (unsigned short)r;
}
__device__ __forceinline__ float bf16_to_f32(unsigned short h) {
    return __uint_as_float(((unsigned int)h) << 16);
}
__device__ __forceinline__ float bf16lo_u32(unsigned int u) {
    return __uint_as_float(u << 16);
}
__device__ __forceinline__ float bf16hi_u32(unsigned int u) {
    return __uint_as_float(u & 0xFFFF0000u);
}
// 8 f32 -> hi/lo bf16 fragment pair
__device__ __forceinline__ void cvt_hilo8(float4 v0, float4 v1, short8& hs, short8& ls) {
    float x[8] = {v0.x, v0.y, v0.z, v0.w, v1.x, v1.y, v1.z, v1.w};
    union { short8 s; unsigned short u[8]; } H, L;
#pragma unroll
    for (int k = 0; k < 8; ++k) {
        unsigned short hi = f32_to_bf16_rne(x[k]);
        H.u[k] = hi;
        L.u[k] = f32_to_bf16_rne(x[k] - bf16_to_f32(hi));
    }
    hs = H.s;
    ls = L.s;
}

// ---------------- degree counting ----------------
__global__ void count_deg(const int* __restrict__ row, int* __restrict__ cnt, int E) {
    int e = blockIdx.x * blockDim.x + threadIdx.x;
    if (e < E) atomicAdd(&cnt[row[e]], 1);
}

// ---------------- 3-phase exclusive scan (for CSR row_start) ----------------
__global__ void scan_phase1(const int* __restrict__ cnt, int* __restrict__ bsum, int n) {
    __shared__ int sdata[256];
    int t = threadIdx.x;
    int i = blockIdx.x * 256 + t;
    sdata[t] = (i < n) ? cnt[i] : 0;
    __syncthreads();
    for (int s = 128; s > 0; s >>= 1) {
        if (t < s) sdata[t] += sdata[t + s];
        __syncthreads();
    }
    if (t == 0) bsum[blockIdx.x] = sdata[0];
}

__global__ void scan_phase2(int* __restrict__ bsum, int nb) {
    __shared__ int sdata[256];
    int t = threadIdx.x;
    int v = (t < nb) ? bsum[t] : 0;
    sdata[t] = v;
    __syncthreads();
    for (int s = 1; s < 256; s <<= 1) {
        int add = (t >= s) ? sdata[t - s] : 0;
        __syncthreads();
        sdata[t] += add;
        __syncthreads();
    }
    if (t < nb) bsum[t] = sdata[t] - v;   // exclusive
}

// scan_phase3 + finalize_deg folded
__global__ void scan_phase3(const int* __restrict__ cnt, const int* __restrict__ bsum,
                            int* __restrict__ row_start, int* __restrict__ fill_pos,
                            float* __restrict__ deg_inv, float* __restrict__ dis,
                            int n, int E) {
    __shared__ int sdata[256];
    int t = threadIdx.x;
    int i = blockIdx.x * 256 + t;
    int v = (i < n) ? cnt[i] : 0;
    sdata[t] = v;
    __syncthreads();
    for (int s = 1; s < 256; s <<= 1) {
        int add = (t >= s) ? sdata[t - s] : 0;
        __syncthreads();
        sdata[t] += add;
        __syncthreads();
    }
    if (i < n) {
        int ex = bsum[blockIdx.x] + sdata[t] - v;
        row_start[i] = ex;
        fill_pos[i] = ex;
        float d = (float)(v + 1);
        deg_inv[i] = 1.0f / d;
        dis[i] = rsqrtf(d);
    }
    if (blockIdx.x == 0 && t == 0) row_start[n] = E;
}

// only csr_col (4B/edge scatter; weights folded into pre-scaled hbf)
__global__ void fill_csr(const int* __restrict__ row, const int* __restrict__ col,
                         int* __restrict__ fill_pos, int* __restrict__ csr_col, int E) {
    int e = blockIdx.x * blockDim.x + threadIdx.x;
    if (e < E) {
        int r = row[e];
        int p = atomicAdd(&fill_pos[r], 1);
        csr_col[p] = col[e];
    }
}

// ---------------- prepack weights into combined hi/lo MFMA B-fragment order -----------
// chunk c = kc*1024 + hl*512 + nt*64 + lane  (8 ushorts per chunk at Wf[c*8])
// value: bf16 hi (hl=0) or lo (hl=1) of W[nt*16+(lane&15)][kc*32+(lane>>4)*8 + j]
// lin: 8 kc -> 8192 chunks; conv: 4 kc -> 4096 chunks.
__global__ void prepack_w(const float* __restrict__ lw, const float* __restrict__ cw,
                          unsigned short* __restrict__ fl, unsigned short* __restrict__ fc) {
    int idx = blockIdx.x * blockDim.x + threadIdx.x;
    const float* src;
    unsigned short* dst;
    int K, c;
    if (idx < 8192) {
        src = lw; dst = fl; K = INF; c = idx;
    } else if (idx < 12288) {
        src = cw; dst = fc; K = HF; c = idx - 8192;
    } else return;
    int lane = c & 63;
    int nt = (c >> 6) & 7;
    int hl = (c >> 9) & 1;
    int kc = c >> 10;
    int rw = nt * 16 + (lane & 15);
    int koff = kc * 32 + (lane >> 4) * 8;
    const float* p = &src[(size_t)rw * K + koff];
    float4 v0 = *reinterpret_cast<const float4*>(p);
    float4 v1 = *reinterpret_cast<const float4*>(p + 4);
    short8 hs, ls;
    cvt_hilo8(v0, v1, hs, ls);
    *reinterpret_cast<short8*>(&dst[(size_t)c * 8]) = hs == hs ? (hl ? ls : hs) : hs;
}

// ---------------- split-bf16 MFMA GEMM, W staged in LDS in 32KB chunks ----------------
// TM=64/block (4 waves x 16 rows), grid 782. W fragments live in LDS (staged 2 kc at a
// time = 32KB, pure uint4 memcpy from prepacked Wf). K-loop: 1 A-load + 16 ds_read_b128
// + 24 MFMA per kc; barriers only at stage boundaries (lin 4 stages, conv 2).
// MODE 0 (lin):   A=f32, convert in regs. C = acc+bias -> f32; Cbf = bf16(dis*C).
// MODE 1 (conv+LN): A=packed hi/lo. v = acc+conv_b+relu(h+root)*deg_inv; x=v+h;
//                   LN; relu -> C (in-place h) f32; Cbf = bf16(dis*C).
// MODE 2 (conv+out): A packed. C = acc+conv_b+relu(h+root)*deg_inv.
template <int K, int MODE>
__global__ __launch_bounds__(256) void gemm_ldsw(
    const float* __restrict__ Af,
    const unsigned short* __restrict__ Ahg, const unsigned short* __restrict__ Alg,
    const unsigned short* __restrict__ Wf,
    const float* __restrict__ bias,
    float* __restrict__ C, unsigned short* __restrict__ Cbf,
    const float* __restrict__ h, const float* __restrict__ deg_inv,
    const float* __restrict__ dis, const float* __restrict__ root,
    const float* __restrict__ gamma, const float* __restrict__ beta,
    int M) {
    constexpr int NKC = K / 32;
    __shared__ unsigned short WS[2 * 8192];   // 2 kc x 16KB = 32KB

    const int t = threadIdx.x;
    const int wave = t >> 6;
    const int lane = t & 63;
    const int lrow = lane & 15;
    const int quad = lane >> 4;
    const int bm = blockIdx.x * 64;
    int arow = bm + wave * 16 + lrow;
    if (arow >= M) arow = M - 1;   // clamp; stores are predicated

    floatx4 acc[8];
#pragma unroll
    for (int nt = 0; nt < 8; ++nt) acc[nt] = (floatx4){0.f, 0.f, 0.f, 0.f};

#pragma unroll
    for (int p = 0; p < NKC / 2; ++p) {
        if (p) __syncthreads();
        // stage 2 kc of W frags: 32KB = 2048 uint4, 8 per thread
        {
            const uint4* src = reinterpret_cast<const uint4*>(Wf + (size_t)p * 16384);
            uint4* dstl = reinterpret_cast<uint4*>(WS);
#pragma unroll
            for (int i = 0; i < 8; ++i) dstl[t + 256 * i] = src[t + 256 * i];
        }
        __syncthreads();
#pragma unroll
        for (int k2 = 0; k2 < 2; ++k2) {
            int kc = p * 2 + k2;
            short8 afh, afl;
            if (MODE == 0) {
                const float* ap = &Af[(size_t)arow * K + kc * 32 + quad * 8];
                float4 a0 = *reinterpret_cast<const float4*>(ap);
                float4 a1 = *reinterpret_cast<const float4*>(ap + 4);
                cvt_hilo8(a0, a1, afh, afl);
            } else {
                size_t ao = (size_t)arow * K + kc * 32 + quad * 8;
                afh = *reinterpret_cast<const short8*>(&Ahg[ao]);
                afl = *reinterpret_cast<const short8*>(&Alg[ao]);
            }
            const unsigned short* wb = &WS[k2 * 8192 + lane * 8];
#pragma unroll
            for (int nt = 0; nt < 8; ++nt) {
                short8 bfh = *reinterpret_cast<const short8*>(wb + nt * 512);
                short8 bfl = *reinterpret_cast<const short8*>(wb + 4096 + nt * 512);
                acc[nt] = __builtin_amdgcn_mfma_f32_16x16x32_bf16(afh, bfh, acc[nt], 0, 0, 0);
                acc[nt] = __builtin_amdgcn_mfma_f32_16x16x32_bf16(afl, bfh, acc[nt], 0, 0, 0);
                acc[nt] = __builtin_amdgcn_mfma_f32_16x16x32_bf16(afh, bfl, acc[nt], 0, 0, 0);
            }
        }
    }

    // per-column constants (col = nt*16 + lrow, fixed across rows)
    float cb[8], rt[8], gm[8], bt[8];
#pragma unroll
    for (int nt = 0; nt < 8; ++nt) {
        int colh = nt * 16 + lrow;
        cb[nt] = bias[colh];
        if (MODE >= 1) rt[nt] = root[colh];
        if (MODE == 1) { gm[nt] = gamma[colh]; bt[nt] = beta[colh]; }
    }

    // epilogue: C/D layout col=lane&15, row=quad*4+r
#pragma unroll
    for (int r = 0; r < 4; ++r) {
        int grow = bm + wave * 16 + quad * 4 + r;
        bool ok = (grow < M);
        int gr = ok ? grow : M - 1;
        float x[8];
        if (MODE == 0) {
#pragma unroll
            for (int nt = 0; nt < 8; ++nt) x[nt] = acc[nt][r] + cb[nt];
        } else {
            float di = deg_inv[gr];
            float hv[8];
#pragma unroll
            for (int nt = 0; nt < 8; ++nt) hv[nt] = h[(size_t)gr * HF + nt * 16 + lrow];
#pragma unroll
            for (int nt = 0; nt < 8; ++nt) {
                float v = acc[nt][r] + cb[nt] + fmaxf(hv[nt] + rt[nt], 0.f) * di;
                x[nt] = (MODE == 1) ? v + hv[nt] : v;   // MODE1: residual with ori=h
            }
        }
        if (MODE == 1) {
            float s = 0.f;
#pragma unroll
            for (int nt = 0; nt < 8; ++nt) s += x[nt];
#pragma unroll
            for (int m = 1; m < 16; m <<= 1) s += __shfl_xor(s, m, 64);
            float mu = s * (1.0f / HF);
            float var = 0.f;
#pragma unroll
            for (int nt = 0; nt < 8; ++nt) { float d = x[nt] - mu; var += d * d; }
#pragma unroll
            for (int m = 1; m < 16; m <<= 1) var += __shfl_xor(var, m, 64);
            float rs = rsqrtf(var * (1.0f / HF) + 1e-5f);
            float ds = dis[gr];
            if (ok) {
#pragma unroll
                for (int nt = 0; nt < 8; ++nt) {
                    int colh = nt * 16 + lrow;
                    float y = fmaxf((x[nt] - mu) * rs * gm[nt] + bt[nt], 0.f);
                    C[(size_t)grow * HF + colh] = y;
                    Cbf[(size_t)grow * HF + colh] = f32_to_bf16_rne(ds * y);
                }
            }
        } else if (MODE == 0) {
            if (ok) {
                float ds = dis[grow];
#pragma unroll
                for (int nt = 0; nt < 8; ++nt) {
                    int colh = nt * 16 + lrow;
                    C[(size_t)grow * HF + colh] = x[nt];
                    Cbf[(size_t)grow * HF + colh] = f32_to_bf16_rne(ds * x[nt]);
                }
            }
        } else {
            if (ok) {
#pragma unroll
                for (int nt = 0; nt < 8; ++nt)
                    C[(size_t)grow * HF + nt * 16 + lrow] = x[nt];
            }
        }
    }
}

// ---------------- aggregate: agg = dis[t]*sum_e hbf[c] + deg_inv[t]*h[t] ----------------
// hbf is pre-scaled by dis[c]; one wave per node, quarter-wave per edge; bf16 hi/lo out.
__global__ void aggregate(const int* __restrict__ row_start, const int* __restrict__ csr_col,
                          const float* __restrict__ dis, const float* __restrict__ deg_inv,
                          const float* __restrict__ h, const unsigned short* __restrict__ hbf,
                          unsigned short* __restrict__ agg_hi, unsigned short* __restrict__ agg_lo,
                          int n) {
    int wid = (blockIdx.x * blockDim.x + threadIdx.x) >> 6;
    int lane = threadIdx.x & 63;
    if (wid >= n) return;
    int q = lane >> 4;
    int l16 = lane & 15;
    int s = row_start[wid];
    int e = row_start[wid + 1];
    float a0 = 0.f, a1 = 0.f, a2 = 0.f, a3 = 0.f, a4 = 0.f, a5 = 0.f, a6 = 0.f, a7 = 0.f;
    for (int j = s + q; j < e; j += 4) {
        int c = csr_col[j];
        uint4 hv = *reinterpret_cast<const uint4*>(&hbf[(size_t)c * HF + l16 * 8]);
        a0 += bf16lo_u32(hv.x);
        a1 += bf16hi_u32(hv.x);
        a2 += bf16lo_u32(hv.y);
        a3 += bf16hi_u32(hv.y);
        a4 += bf16lo_u32(hv.z);
        a5 += bf16hi_u32(hv.z);
        a6 += bf16lo_u32(hv.w);
        a7 += bf16hi_u32(hv.w);
    }
#pragma unroll
    for (int m = 16; m < 64; m <<= 1) {
        a0 += __shfl_xor(a0, m, 64);
        a1 += __shfl_xor(a1, m, 64);
        a2 += __shfl_xor(a2, m, 64);
        a3 += __shfl_xor(a3, m, 64);
        a4 += __shfl_xor(a4, m, 64);
        a5 += __shfl_xor(a5, m, 64);
        a6 += __shfl_xor(a6, m, 64);
        a7 += __shfl_xor(a7, m, 64);
    }
    if (q == 0) {
        float dn = dis[wid];
        float di = deg_inv[wid];
        float4 hA = *reinterpret_cast<const float4*>(&h[(size_t)wid * HF + l16 * 8]);
        float4 hB = *reinterpret_cast<const float4*>(&h[(size_t)wid * HF + l16 * 8 + 4]);
        float o[8];
        o[0] = fmaf(dn, a0, di * hA.x);
        o[1] = fmaf(dn, a1, di * hA.y);
        o[2] = fmaf(dn, a2, di * hA.z);
        o[3] = fmaf(dn, a3, di * hA.w);
        o[4] = fmaf(dn, a4, di * hB.x);
        o[5] = fmaf(dn, a5, di * hB.y);
        o[6] = fmaf(dn, a6, di * hB.z);
        o[7] = fmaf(dn, a7, di * hB.w);
        unsigned short hi[8], lo[8];
#pragma unroll
        for (int k = 0; k < 8; ++k) {
            hi[k] = f32_to_bf16_rne(o[k]);
            lo[k] = f32_to_bf16_rne(o[k] - bf16_to_f32(hi[k]));
        }
        uint4 hp, lp;
        hp.x = (unsigned)hi[0] | ((unsigned)hi[1] << 16);
        hp.y = (unsigned)hi[2] | ((unsigned)hi[3] << 16);
        hp.z = (unsigned)hi[4] | ((unsigned)hi[5] << 16);
        hp.w = (unsigned)hi[6] | ((unsigned)hi[7] << 16);
        lp.x = (unsigned)lo[0] | ((unsigned)lo[1] << 16);
        lp.y = (unsigned)lo[2] | ((unsigned)lo[3] << 16);
        lp.z = (unsigned)lo[4] | ((unsigned)lo[5] << 16);
        lp.w = (unsigned)lo[6] | ((unsigned)lo[7] << 16);
        *reinterpret_cast<uint4*>(&agg_hi[(size_t)wid * HF + l16 * 8]) = hp;
        *reinterpret_cast<uint4*>(&agg_lo[(size_t)wid * HF + l16 * 8]) = lp;
    }
}

extern "C" void kernel_launch(void* const* d_in, const int* in_sizes, int n_in,
                              void* d_out, int out_size, void* d_ws, size_t ws_size,
                              hipStream_t stream) {
    const int N = NN, E = EE;
    const float* in_feat = (const float*)d_in[0];
    const int* row = (const int*)d_in[1];
    const int* col = (const int*)d_in[2];
    const float* lin_w = (const float*)d_in[3];
    const float* lin_b = (const float*)d_in[4];
    const float* conv_w = (const float*)d_in[5];
    const float* conv_b = (const float*)d_in[6];
    const float* root_emb = (const float*)d_in[7];
    const float* ln_gamma = (const float*)d_in[8];
    const float* ln_beta = (const float*)d_in[9];
    float* out = (float*)d_out;

    // workspace layout (4B units); all segments kept 16B-aligned
    float* ws = (float*)d_ws;
    size_t o = 0;
    float* deg_inv = ws + o; o += N;
    float* dis = ws + o; o += N;
    int* cnt = (int*)(ws + o); o += N;
    int* row_start = (int*)(ws + o); o += N + 4;
    int* fill_pos = (int*)(ws + o); o += N;
    int* bsum = (int*)(ws + o); o += 256;
    int* csr_col = (int*)(ws + o); o += E;
    o = (o + 3) & ~(size_t)3;
    unsigned short* fl = (unsigned short*)(ws + o); o += 32768;  // 65536 ushort (128KB)
    unsigned short* fc = (unsigned short*)(ws + o); o += 16384;  // 32768 ushort (64KB)
    float* h0 = ws + o; o += (size_t)N * HF;
    unsigned short* hbf = (unsigned short*)(ws + o); o += (size_t)N * HF / 2;
    unsigned short* agg_hi = (unsigned short*)(ws + o); o += (size_t)N * HF / 2;
    unsigned short* agg_lo = (unsigned short*)(ws + o); o += (size_t)N * HF / 2;

    const int NB = (N + 255) / 256;

    hipMemsetAsync(cnt, 0, N * sizeof(int), stream);
    count_deg<<<(E + 255) / 256, 256, 0, stream>>>(row, cnt, E);
    scan_phase1<<<NB, 256, 0, stream>>>(cnt, bsum, N);
    scan_phase2<<<1, 256, 0, stream>>>(bsum, NB);
    scan_phase3<<<NB, 256, 0, stream>>>(cnt, bsum, row_start, fill_pos, deg_inv, dis, N, E);
    fill_csr<<<(E + 255) / 256, 256, 0, stream>>>(row, col, fill_pos, csr_col, E);
    prepack_w<<<48, 256, 0, stream>>>(lin_w, conv_w, fl, fc);

    const int GB = (N + 63) / 64;
    const int WB = (N + 3) / 4;

    // h0 = in_feat @ lin_w.T + lin_b  (f32 + dis-scaled bf16 copy)
    gemm_ldsw<INF, 0><<<GB, 256, 0, stream>>>(in_feat, nullptr, nullptr, fl, lin_b,
                                              h0, hbf, nullptr, nullptr, dis, nullptr,
                                              nullptr, nullptr, N);

    // ---- prop step 0 (conv + fused residual/LN/ReLU epilogue -> h0 in-place) ----
    aggregate<<<WB, 256, 0, stream>>>(row_start, csr_col, dis, deg_inv, h0, hbf,
                                      agg_hi, agg_lo, N);
    gemm_ldsw<HF, 1><<<GB, 256, 0, stream>>>(nullptr, agg_hi, agg_lo, fc, conv_b,
                                             h0, hbf, h0, deg_inv, dis, root_emb,
                                             ln_gamma + HF, ln_beta + HF, N);

    // ---- prop step 1 (conv + combine epilogue -> out) ----
    aggregate<<<WB, 256, 0, stream>>>(row_start, csr_col, dis, deg_inv, h0, hbf,
                                      agg_hi, agg_lo, N);
    gemm_ldsw<HF, 2><<<GB, 256, 0, stream>>>(nullptr, agg_hi, agg_lo, fc, conv_b,
                                             out, nullptr, h0, deg_inv, dis, root_emb,
                                             nullptr, nullptr, N);
}

// Round 7
// 312.563 us; speedup vs baseline: 1.0608x; 1.0011x over previous
//
#include <hip/hip_runtime.h>

#define NN 50000
#define EE 600000
#define INF 256
#define HF 128
#define CEB ((EE + 255) / 256)   // 2344 blocks for edge-parallel work

typedef __attribute__((ext_vector_type(8))) short short8;
typedef __attribute__((ext_vector_type(4))) float floatx4;

// ---------------- bf16 helpers ----------------
__device__ __forceinline__ unsigned short f32_to_bf16_rne(float x) {
    unsigned int u = __float_as_uint(x);
    unsigned int r = (u + 0x7FFFu + ((u >> 16) & 1u)) >> 16;
    return (unsigned short)r;
}
__device__ __forceinline__ float bf16_to_f32(unsigned short h) {
    return __uint_as_float(((unsigned int)h) << 16);
}
__device__ __forceinline__ float bf16lo_u32(unsigned int u) {
    return __uint_as_float(u << 16);
}
__device__ __forceinline__ float bf16hi_u32(unsigned int u) {
    return __uint_as_float(u & 0xFFFF0000u);
}
// 8 f32 -> hi/lo bf16 fragment pair
__device__ __forceinline__ void cvt_hilo8(float4 v0, float4 v1, short8& hs, short8& ls) {
    float x[8] = {v0.x, v0.y, v0.z, v0.w, v1.x, v1.y, v1.z, v1.w};
    union { short8 s; unsigned short u[8]; } H, L;
#pragma unroll
    for (int k = 0; k < 8; ++k) {
        unsigned short hi = f32_to_bf16_rne(x[k]);
        H.u[k] = hi;
        L.u[k] = f32_to_bf16_rne(x[k] - bf16_to_f32(hi));
    }
    hs = H.s;
    ls = L.s;
}

// ---------------- fused: degree counting + weight prepack (independent work) -----------
// blocks [0,CEB): count in-degree. blocks [CEB, CEB+48): prepack weights into combined
// hi/lo MFMA B-fragment order: chunk c = kc*1024 + hl*512 + nt*64 + lane (8 ushorts),
// value = bf16 hi(hl=0)/lo(hl=1) of W[nt*16+(lane&15)][kc*32+(lane>>4)*8+j].
__global__ void count_and_prepack(const int* __restrict__ row, int* __restrict__ cnt, int E,
                                  const float* __restrict__ lw, const float* __restrict__ cw,
                                  unsigned short* __restrict__ fl, unsigned short* __restrict__ fc) {
    int b = blockIdx.x;
    if (b < CEB) {
        int e = b * 256 + threadIdx.x;
        if (e < E) atomicAdd(&cnt[row[e]], 1);
        return;
    }
    int idx = (b - CEB) * 256 + threadIdx.x;
    const float* src;
    unsigned short* dst;
    int K, c;
    if (idx < 8192) {
        src = lw; dst = fl; K = INF; c = idx;
    } else if (idx < 12288) {
        src = cw; dst = fc; K = HF; c = idx - 8192;
    } else return;
    int lane = c & 63;
    int nt = (c >> 6) & 7;
    int hl = (c >> 9) & 1;
    int kc = c >> 10;
    int rw = nt * 16 + (lane & 15);
    int koff = kc * 32 + (lane >> 4) * 8;
    const float* p = &src[(size_t)rw * K + koff];
    float4 v0 = *reinterpret_cast<const float4*>(p);
    float4 v1 = *reinterpret_cast<const float4*>(p + 4);
    short8 hs, ls;
    cvt_hilo8(v0, v1, hs, ls);
    *reinterpret_cast<short8*>(&dst[(size_t)c * 8]) = hl ? ls : hs;
}

// ---------------- scan phase1: per-block sums of cnt ----------------
__global__ void scan_phase1(const int* __restrict__ cnt, int* __restrict__ bsum, int n) {
    __shared__ int sdata[256];
    int t = threadIdx.x;
    int i = blockIdx.x * 256 + t;
    sdata[t] = (i < n) ? cnt[i] : 0;
    __syncthreads();
    for (int s = 128; s > 0; s >>= 1) {
        if (t < s) sdata[t] += sdata[t + s];
        __syncthreads();
    }
    if (t == 0) bsum[blockIdx.x] = sdata[0];
}

// ---------------- scan phase2+3 fused (+ finalize_deg): every block re-scans bsum ------
__global__ void scan_phase3(const int* __restrict__ cnt, const int* __restrict__ bsum,
                            int* __restrict__ row_start, int* __restrict__ fill_pos,
                            float* __restrict__ deg_inv, float* __restrict__ dis,
                            int n, int nb, int E) {
    __shared__ int sb[256];
    __shared__ int sdata[256];
    int t = threadIdx.x;
    // inclusive scan of block sums (nb <= 256), redundantly in every block
    sb[t] = (t < nb) ? bsum[t] : 0;
    __syncthreads();
    for (int s = 1; s < 256; s <<= 1) {
        int add = (t >= s) ? sb[t - s] : 0;
        __syncthreads();
        sb[t] += add;
        __syncthreads();
    }
    int base = sb[blockIdx.x] - bsum[blockIdx.x];   // exclusive prefix of this block
    // per-block inclusive scan of cnt
    int i = blockIdx.x * 256 + t;
    int v = (i < n) ? cnt[i] : 0;
    sdata[t] = v;
    __syncthreads();
    for (int s = 1; s < 256; s <<= 1) {
        int add = (t >= s) ? sdata[t - s] : 0;
        __syncthreads();
        sdata[t] += add;
        __syncthreads();
    }
    if (i < n) {
        int ex = base + sdata[t] - v;
        row_start[i] = ex;
        fill_pos[i] = ex;
        float d = (float)(v + 1);
        deg_inv[i] = 1.0f / d;
        dis[i] = rsqrtf(d);
    }
    if (blockIdx.x == 0 && t == 0) row_start[n] = E;
}

// only csr_col (4B/edge scatter; weights folded into pre-scaled hbf); nt store hint
__global__ void fill_csr(const int* __restrict__ row, const int* __restrict__ col,
                         int* __restrict__ fill_pos, int* __restrict__ csr_col, int E) {
    int e = blockIdx.x * blockDim.x + threadIdx.x;
    if (e < E) {
        int r = row[e];
        int p = atomicAdd(&fill_pos[r], 1);
        __builtin_nontemporal_store(col[e], &csr_col[p]);
    }
}

// ---------------- split-bf16 MFMA GEMM, W staged in LDS in 32KB chunks ----------------
// TM=64/block (4 waves x 16 rows), grid 782. W fragments live in LDS (staged 2 kc at a
// time = 32KB, pure uint4 memcpy from prepacked Wf). K-loop: 1 A-load + 16 ds_read_b128
// + 24 MFMA per kc; barriers only at stage boundaries (lin 4 stages, conv 2).
// MODE 0 (lin):   A=f32, convert in regs. C = acc+bias -> f32; Cbf = bf16(dis*C).
// MODE 1 (conv+LN): A=packed hi/lo. v = acc+conv_b+relu(h+root)*deg_inv; x=v+h;
//                   LN; relu -> C (in-place h) f32; Cbf = bf16(dis*C).
// MODE 2 (conv+out): A packed. C = acc+conv_b+relu(h+root)*deg_inv.
template <int K, int MODE>
__global__ __launch_bounds__(256) void gemm_ldsw(
    const float* __restrict__ Af,
    const unsigned short* __restrict__ Ahg, const unsigned short* __restrict__ Alg,
    const unsigned short* __restrict__ Wf,
    const float* __restrict__ bias,
    float* __restrict__ C, unsigned short* __restrict__ Cbf,
    const float* __restrict__ h, const float* __restrict__ deg_inv,
    const float* __restrict__ dis, const float* __restrict__ root,
    const float* __restrict__ gamma, const float* __restrict__ beta,
    int M) {
    constexpr int NKC = K / 32;
    __shared__ unsigned short WS[2 * 8192];   // 2 kc x 16KB = 32KB

    const int t = threadIdx.x;
    const int wave = t >> 6;
    const int lane = t & 63;
    const int lrow = lane & 15;
    const int quad = lane >> 4;
    const int bm = blockIdx.x * 64;
    int arow = bm + wave * 16 + lrow;
    if (arow >= M) arow = M - 1;   // clamp; stores are predicated

    floatx4 acc[8];
#pragma unroll
    for (int nt = 0; nt < 8; ++nt) acc[nt] = (floatx4){0.f, 0.f, 0.f, 0.f};

#pragma unroll
    for (int p = 0; p < NKC / 2; ++p) {
        if (p) __syncthreads();
        // stage 2 kc of W frags: 32KB = 2048 uint4, 8 per thread
        {
            const uint4* src = reinterpret_cast<const uint4*>(Wf + (size_t)p * 16384);
            uint4* dstl = reinterpret_cast<uint4*>(WS);
#pragma unroll
            for (int i = 0; i < 8; ++i) dstl[t + 256 * i] = src[t + 256 * i];
        }
        __syncthreads();
#pragma unroll
        for (int k2 = 0; k2 < 2; ++k2) {
            int kc = p * 2 + k2;
            short8 afh, afl;
            if (MODE == 0) {
                const float* ap = &Af[(size_t)arow * K + kc * 32 + quad * 8];
                float4 a0 = *reinterpret_cast<const float4*>(ap);
                float4 a1 = *reinterpret_cast<const float4*>(ap + 4);
                cvt_hilo8(a0, a1, afh, afl);
            } else {
                size_t ao = (size_t)arow * K + kc * 32 + quad * 8;
                afh = *reinterpret_cast<const short8*>(&Ahg[ao]);
                afl = *reinterpret_cast<const short8*>(&Alg[ao]);
            }
            const unsigned short* wb = &WS[k2 * 8192 + lane * 8];
#pragma unroll
            for (int nt = 0; nt < 8; ++nt) {
                short8 bfh = *reinterpret_cast<const short8*>(wb + nt * 512);
                short8 bfl = *reinterpret_cast<const short8*>(wb + 4096 + nt * 512);
                acc[nt] = __builtin_amdgcn_mfma_f32_16x16x32_bf16(afh, bfh, acc[nt], 0, 0, 0);
                acc[nt] = __builtin_amdgcn_mfma_f32_16x16x32_bf16(afl, bfh, acc[nt], 0, 0, 0);
                acc[nt] = __builtin_amdgcn_mfma_f32_16x16x32_bf16(afh, bfl, acc[nt], 0, 0, 0);
            }
        }
    }

    // per-column constants (col = nt*16 + lrow, fixed across rows)
    float cb[8], rt[8], gm[8], bt[8];
#pragma unroll
    for (int nt = 0; nt < 8; ++nt) {
        int colh = nt * 16 + lrow;
        cb[nt] = bias[colh];
        if (MODE >= 1) rt[nt] = root[colh];
        if (MODE == 1) { gm[nt] = gamma[colh]; bt[nt] = beta[colh]; }
    }

    // epilogue: C/D layout col=lane&15, row=quad*4+r
#pragma unroll
    for (int r = 0; r < 4; ++r) {
        int grow = bm + wave * 16 + quad * 4 + r;
        bool ok = (grow < M);
        int gr = ok ? grow : M - 1;
        float x[8];
        if (MODE == 0) {
#pragma unroll
            for (int nt = 0; nt < 8; ++nt) x[nt] = acc[nt][r] + cb[nt];
        } else {
            float di = deg_inv[gr];
            float hv[8];
#pragma unroll
            for (int nt = 0; nt < 8; ++nt) hv[nt] = h[(size_t)gr * HF + nt * 16 + lrow];
#pragma unroll
            for (int nt = 0; nt < 8; ++nt) {
                float v = acc[nt][r] + cb[nt] + fmaxf(hv[nt] + rt[nt], 0.f) * di;
                x[nt] = (MODE == 1) ? v + hv[nt] : v;   // MODE1: residual with ori=h
            }
        }
        if (MODE == 1) {
            float s = 0.f;
#pragma unroll
            for (int nt = 0; nt < 8; ++nt) s += x[nt];
#pragma unroll
            for (int m = 1; m < 16; m <<= 1) s += __shfl_xor(s, m, 64);
            float mu = s * (1.0f / HF);
            float var = 0.f;
#pragma unroll
            for (int nt = 0; nt < 8; ++nt) { float d = x[nt] - mu; var += d * d; }
#pragma unroll
            for (int m = 1; m < 16; m <<= 1) var += __shfl_xor(var, m, 64);
            float rs = rsqrtf(var * (1.0f / HF) + 1e-5f);
            float ds = dis[gr];
            if (ok) {
#pragma unroll
                for (int nt = 0; nt < 8; ++nt) {
                    int colh = nt * 16 + lrow;
                    float y = fmaxf((x[nt] - mu) * rs * gm[nt] + bt[nt], 0.f);
                    C[(size_t)grow * HF + colh] = y;
                    Cbf[(size_t)grow * HF + colh] = f32_to_bf16_rne(ds * y);
                }
            }
        } else if (MODE == 0) {
            if (ok) {
                float ds = dis[grow];
#pragma unroll
                for (int nt = 0; nt < 8; ++nt) {
                    int colh = nt * 16 + lrow;
                    C[(size_t)grow * HF + colh] = x[nt];
                    Cbf[(size_t)grow * HF + colh] = f32_to_bf16_rne(ds * x[nt]);
                }
            }
        } else {
            if (ok) {
#pragma unroll
                for (int nt = 0; nt < 8; ++nt)
                    C[(size_t)grow * HF + nt * 16 + lrow] = x[nt];
            }
        }
    }
}

// ---------------- aggregate: agg = dis[t]*sum_e hbf[c] + deg_inv[t]*h[t] ----------------
// hbf pre-scaled by dis[c]; one wave per node, quarter-wave per edge, 2-edge unroll
// (8 independent 16B gathers in flight per wave); bf16 hi/lo packed output.
__global__ void aggregate(const int* __restrict__ row_start, const int* __restrict__ csr_col,
                          const float* __restrict__ dis, const float* __restrict__ deg_inv,
                          const float* __restrict__ h, const unsigned short* __restrict__ hbf,
                          unsigned short* __restrict__ agg_hi, unsigned short* __restrict__ agg_lo,
                          int n) {
    int wid = (blockIdx.x * blockDim.x + threadIdx.x) >> 6;
    int lane = threadIdx.x & 63;
    if (wid >= n) return;
    int q = lane >> 4;
    int l16 = lane & 15;
    int s = row_start[wid];
    int e = row_start[wid + 1];
    float a0 = 0.f, a1 = 0.f, a2 = 0.f, a3 = 0.f, a4 = 0.f, a5 = 0.f, a6 = 0.f, a7 = 0.f;
    float b0 = 0.f, b1 = 0.f, b2 = 0.f, b3 = 0.f, b4 = 0.f, b5 = 0.f, b6 = 0.f, b7 = 0.f;
    int j = s + q;
    for (; j + 4 < e; j += 8) {
        int c0 = csr_col[j];
        int c1 = csr_col[j + 4];
        uint4 h0 = *reinterpret_cast<const uint4*>(&hbf[(size_t)c0 * HF + l16 * 8]);
        uint4 h1 = *reinterpret_cast<const uint4*>(&hbf[(size_t)c1 * HF + l16 * 8]);
        a0 += bf16lo_u32(h0.x); a1 += bf16hi_u32(h0.x);
        a2 += bf16lo_u32(h0.y); a3 += bf16hi_u32(h0.y);
        a4 += bf16lo_u32(h0.z); a5 += bf16hi_u32(h0.z);
        a6 += bf16lo_u32(h0.w); a7 += bf16hi_u32(h0.w);
        b0 += bf16lo_u32(h1.x); b1 += bf16hi_u32(h1.x);
        b2 += bf16lo_u32(h1.y); b3 += bf16hi_u32(h1.y);
        b4 += bf16lo_u32(h1.z); b5 += bf16hi_u32(h1.z);
        b6 += bf16lo_u32(h1.w); b7 += bf16hi_u32(h1.w);
    }
    if (j < e) {
        int c0 = csr_col[j];
        uint4 h0 = *reinterpret_cast<const uint4*>(&hbf[(size_t)c0 * HF + l16 * 8]);
        a0 += bf16lo_u32(h0.x); a1 += bf16hi_u32(h0.x);
        a2 += bf16lo_u32(h0.y); a3 += bf16hi_u32(h0.y);
        a4 += bf16lo_u32(h0.z); a5 += bf16hi_u32(h0.z);
        a6 += bf16lo_u32(h0.w); a7 += bf16hi_u32(h0.w);
    }
    a0 += b0; a1 += b1; a2 += b2; a3 += b3;
    a4 += b4; a5 += b5; a6 += b6; a7 += b7;
#pragma unroll
    for (int m = 16; m < 64; m <<= 1) {
        a0 += __shfl_xor(a0, m, 64);
        a1 += __shfl_xor(a1, m, 64);
        a2 += __shfl_xor(a2, m, 64);
        a3 += __shfl_xor(a3, m, 64);
        a4 += __shfl_xor(a4, m, 64);
        a5 += __shfl_xor(a5, m, 64);
        a6 += __shfl_xor(a6, m, 64);
        a7 += __shfl_xor(a7, m, 64);
    }
    if (q == 0) {
        float dn = dis[wid];
        float di = deg_inv[wid];
        float4 hA = *reinterpret_cast<const float4*>(&h[(size_t)wid * HF + l16 * 8]);
        float4 hB = *reinterpret_cast<const float4*>(&h[(size_t)wid * HF + l16 * 8 + 4]);
        float o[8];
        o[0] = fmaf(dn, a0, di * hA.x);
        o[1] = fmaf(dn, a1, di * hA.y);
        o[2] = fmaf(dn, a2, di * hA.z);
        o[3] = fmaf(dn, a3, di * hA.w);
        o[4] = fmaf(dn, a4, di * hB.x);
        o[5] = fmaf(dn, a5, di * hB.y);
        o[6] = fmaf(dn, a6, di * hB.z);
        o[7] = fmaf(dn, a7, di * hB.w);
        unsigned short hi[8], lo[8];
#pragma unroll
        for (int k = 0; k < 8; ++k) {
            hi[k] = f32_to_bf16_rne(o[k]);
            lo[k] = f32_to_bf16_rne(o[k] - bf16_to_f32(hi[k]));
        }
        uint4 hp, lp;
        hp.x = (unsigned)hi[0] | ((unsigned)hi[1] << 16);
        hp.y = (unsigned)hi[2] | ((unsigned)hi[3] << 16);
        hp.z = (unsigned)hi[4] | ((unsigned)hi[5] << 16);
        hp.w = (unsigned)hi[6] | ((unsigned)hi[7] << 16);
        lp.x = (unsigned)lo[0] | ((unsigned)lo[1] << 16);
        lp.y = (unsigned)lo[2] | ((unsigned)lo[3] << 16);
        lp.z = (unsigned)lo[4] | ((unsigned)lo[5] << 16);
        lp.w = (unsigned)lo[6] | ((unsigned)lo[7] << 16);
        *reinterpret_cast<uint4*>(&agg_hi[(size_t)wid * HF + l16 * 8]) = hp;
        *reinterpret_cast<uint4*>(&agg_lo[(size_t)wid * HF + l16 * 8]) = lp;
    }
}

extern "C" void kernel_launch(void* const* d_in, const int* in_sizes, int n_in,
                              void* d_out, int out_size, void* d_ws, size_t ws_size,
                              hipStream_t stream) {
    const int N = NN, E = EE;
    const float* in_feat = (const float*)d_in[0];
    const int* row = (const int*)d_in[1];
    const int* col = (const int*)d_in[2];
    const float* lin_w = (const float*)d_in[3];
    const float* lin_b = (const float*)d_in[4];
    const float* conv_w = (const float*)d_in[5];
    const float* conv_b = (const float*)d_in[6];
    const float* root_emb = (const float*)d_in[7];
    const float* ln_gamma = (const float*)d_in[8];
    const float* ln_beta = (const float*)d_in[9];
    float* out = (float*)d_out;

    // workspace layout (4B units); all segments kept 16B-aligned
    float* ws = (float*)d_ws;
    size_t o = 0;
    float* deg_inv = ws + o; o += N;
    float* dis = ws + o; o += N;
    int* cnt = (int*)(ws + o); o += N;
    int* row_start = (int*)(ws + o); o += N + 4;
    int* fill_pos = (int*)(ws + o); o += N;
    int* bsum = (int*)(ws + o); o += 256;
    int* csr_col = (int*)(ws + o); o += E;
    o = (o + 3) & ~(size_t)3;
    unsigned short* fl = (unsigned short*)(ws + o); o += 32768;  // 65536 ushort (128KB)
    unsigned short* fc = (unsigned short*)(ws + o); o += 16384;  // 32768 ushort (64KB)
    float* h0 = ws + o; o += (size_t)N * HF;
    unsigned short* hbf = (unsigned short*)(ws + o); o += (size_t)N * HF / 2;
    unsigned short* agg_hi = (unsigned short*)(ws + o); o += (size_t)N * HF / 2;
    unsigned short* agg_lo = (unsigned short*)(ws + o); o += (size_t)N * HF / 2;

    const int NB = (N + 255) / 256;   // 196

    hipMemsetAsync(cnt, 0, N * sizeof(int), stream);
    count_and_prepack<<<CEB + 48, 256, 0, stream>>>(row, cnt, E, lin_w, conv_w, fl, fc);
    scan_phase1<<<NB, 256, 0, stream>>>(cnt, bsum, N);
    scan_phase3<<<NB, 256, 0, stream>>>(cnt, bsum, row_start, fill_pos, deg_inv, dis, N, NB, E);
    fill_csr<<<CEB, 256, 0, stream>>>(row, col, fill_pos, csr_col, E);

    const int GB = (N + 63) / 64;
    const int WB = (N + 3) / 4;

    // h0 = in_feat @ lin_w.T + lin_b  (f32 + dis-scaled bf16 copy)
    gemm_ldsw<INF, 0><<<GB, 256, 0, stream>>>(in_feat, nullptr, nullptr, fl, lin_b,
                                              h0, hbf, nullptr, nullptr, dis, nullptr,
                                              nullptr, nullptr, N);

    // ---- prop step 0 (conv + fused residual/LN/ReLU epilogue -> h0 in-place) ----
    aggregate<<<WB, 256, 0, stream>>>(row_start, csr_col, dis, deg_inv, h0, hbf,
                                      agg_hi, agg_lo, N);
    gemm_ldsw<HF, 1><<<GB, 256, 0, stream>>>(nullptr, agg_hi, agg_lo, fc, conv_b,
                                             h0, hbf, h0, deg_inv, dis, root_emb,
                                             ln_gamma + HF, ln_beta + HF, N);

    // ---- prop step 1 (conv + combine epilogue -> out) ----
    aggregate<<<WB, 256, 0, stream>>>(row_start, csr_col, dis, deg_inv, h0, hbf,
                                      agg_hi, agg_lo, N);
    gemm_ldsw<HF, 2><<<GB, 256, 0, stream>>>(nullptr, agg_hi, agg_lo, fc, conv_b,
                                             out, nullptr, h0, deg_inv, dis, root_emb,
                                             nullptr, nullptr, N);
}

// Round 8
// 311.077 us; speedup vs baseline: 1.0659x; 1.0048x over previous
//
#include <hip/hip_runtime.h>

#define NN 50000
#define EE 600000
#define INF 256
#define HF 128
#define CEB ((EE + 255) / 256)   // 2344 blocks for edge-parallel work

typedef __attribute__((ext_vector_type(8))) short short8;
typedef __attribute__((ext_vector_type(4))) float floatx4;

// ---------------- bf16 helpers ----------------
__device__ __forceinline__ unsigned short f32_to_bf16_rne(float x) {
    unsigned int u = __float_as_uint(x);
    unsigned int r = (u + 0x7FFFu + ((u >> 16) & 1u)) >> 16;
    return (unsigned short)r;
}
__device__ __forceinline__ float bf16_to_f32(unsigned short h) {
    return __uint_as_float(((unsigned int)h) << 16);
}
__device__ __forceinline__ float bf16lo_u32(unsigned int u) {
    return __uint_as_float(u << 16);
}
__device__ __forceinline__ float bf16hi_u32(unsigned int u) {
    return __uint_as_float(u & 0xFFFF0000u);
}
// 8 f32 -> hi/lo bf16 fragment pair
__device__ __forceinline__ void cvt_hilo8(float4 v0, float4 v1, short8& hs, short8& ls) {
    float x[8] = {v0.x, v0.y, v0.z, v0.w, v1.x, v1.y, v1.z, v1.w};
    union { short8 s; unsigned short u[8]; } H, L;
#pragma unroll
    for (int k = 0; k < 8; ++k) {
        unsigned short hi = f32_to_bf16_rne(x[k]);
        H.u[k] = hi;
        L.u[k] = f32_to_bf16_rne(x[k] - bf16_to_f32(hi));
    }
    hs = H.s;
    ls = L.s;
}

// ---------------- fused: degree counting + weight prepack (independent work) -----------
__global__ void count_and_prepack(const int* __restrict__ row, int* __restrict__ cnt, int E,
                                  const float* __restrict__ lw, const float* __restrict__ cw,
                                  unsigned short* __restrict__ fl, unsigned short* __restrict__ fc) {
    int b = blockIdx.x;
    if (b < CEB) {
        int e = b * 256 + threadIdx.x;
        if (e < E) atomicAdd(&cnt[row[e]], 1);
        return;
    }
    int idx = (b - CEB) * 256 + threadIdx.x;
    const float* src;
    unsigned short* dst;
    int K, c;
    if (idx < 8192) {
        src = lw; dst = fl; K = INF; c = idx;
    } else if (idx < 12288) {
        src = cw; dst = fc; K = HF; c = idx - 8192;
    } else return;
    int lane = c & 63;
    int nt = (c >> 6) & 7;
    int hl = (c >> 9) & 1;
    int kc = c >> 10;
    int rw = nt * 16 + (lane & 15);
    int koff = kc * 32 + (lane >> 4) * 8;
    const float* p = &src[(size_t)rw * K + koff];
    float4 v0 = *reinterpret_cast<const float4*>(p);
    float4 v1 = *reinterpret_cast<const float4*>(p + 4);
    short8 hs, ls;
    cvt_hilo8(v0, v1, hs, ls);
    *reinterpret_cast<short8*>(&dst[(size_t)c * 8]) = hl ? ls : hs;
}

// ---------------- scan phase1: per-block sums of cnt ----------------
__global__ void scan_phase1(const int* __restrict__ cnt, int* __restrict__ bsum, int n) {
    __shared__ int sdata[256];
    int t = threadIdx.x;
    int i = blockIdx.x * 256 + t;
    sdata[t] = (i < n) ? cnt[i] : 0;
    __syncthreads();
    for (int s = 128; s > 0; s >>= 1) {
        if (t < s) sdata[t] += sdata[t + s];
        __syncthreads();
    }
    if (t == 0) bsum[blockIdx.x] = sdata[0];
}

// ---------------- scan phase2+3 fused (+ finalize_deg): every block re-scans bsum ------
__global__ void scan_phase3(const int* __restrict__ cnt, const int* __restrict__ bsum,
                            int* __restrict__ row_start, int* __restrict__ fill_pos,
                            float* __restrict__ deg_inv, float* __restrict__ dis,
                            int n, int nb, int E) {
    __shared__ int sb[256];
    __shared__ int sdata[256];
    int t = threadIdx.x;
    sb[t] = (t < nb) ? bsum[t] : 0;
    __syncthreads();
    for (int s = 1; s < 256; s <<= 1) {
        int add = (t >= s) ? sb[t - s] : 0;
        __syncthreads();
        sb[t] += add;
        __syncthreads();
    }
    int base = sb[blockIdx.x] - bsum[blockIdx.x];
    int i = blockIdx.x * 256 + t;
    int v = (i < n) ? cnt[i] : 0;
    sdata[t] = v;
    __syncthreads();
    for (int s = 1; s < 256; s <<= 1) {
        int add = (t >= s) ? sdata[t - s] : 0;
        __syncthreads();
        sdata[t] += add;
        __syncthreads();
    }
    if (i < n) {
        int ex = base + sdata[t] - v;
        row_start[i] = ex;
        fill_pos[i] = ex;
        float d = (float)(v + 1);
        deg_inv[i] = 1.0f / d;
        dis[i] = rsqrtf(d);
    }
    if (blockIdx.x == 0 && t == 0) row_start[n] = E;
}

// only csr_col (4B/edge scatter); nt store hint
__global__ void fill_csr(const int* __restrict__ row, const int* __restrict__ col,
                         int* __restrict__ fill_pos, int* __restrict__ csr_col, int E) {
    int e = blockIdx.x * blockDim.x + threadIdx.x;
    if (e < E) {
        int r = row[e];
        int p = atomicAdd(&fill_pos[r], 1);
        __builtin_nontemporal_store(col[e], &csr_col[p]);
    }
}

// ---------------- split-bf16 MFMA GEMM, W staged in LDS in 32KB chunks ----------------
template <int K, int MODE>
__global__ __launch_bounds__(256) void gemm_ldsw(
    const float* __restrict__ Af,
    const unsigned short* __restrict__ Ahg, const unsigned short* __restrict__ Alg,
    const unsigned short* __restrict__ Wf,
    const float* __restrict__ bias,
    float* __restrict__ C, unsigned short* __restrict__ Cbf,
    const float* __restrict__ h, const float* __restrict__ deg_inv,
    const float* __restrict__ dis, const float* __restrict__ root,
    const float* __restrict__ gamma, const float* __restrict__ beta,
    int M) {
    constexpr int NKC = K / 32;
    __shared__ unsigned short WS[2 * 8192];   // 2 kc x 16KB = 32KB

    const int t = threadIdx.x;
    const int wave = t >> 6;
    const int lane = t & 63;
    const int lrow = lane & 15;
    const int quad = lane >> 4;
    const int bm = blockIdx.x * 64;
    int arow = bm + wave * 16 + lrow;
    if (arow >= M) arow = M - 1;   // clamp; stores are predicated

    floatx4 acc[8];
#pragma unroll
    for (int nt = 0; nt < 8; ++nt) acc[nt] = (floatx4){0.f, 0.f, 0.f, 0.f};

#pragma unroll
    for (int p = 0; p < NKC / 2; ++p) {
        if (p) __syncthreads();
        {
            const uint4* src = reinterpret_cast<const uint4*>(Wf + (size_t)p * 16384);
            uint4* dstl = reinterpret_cast<uint4*>(WS);
#pragma unroll
            for (int i = 0; i < 8; ++i) dstl[t + 256 * i] = src[t + 256 * i];
        }
        __syncthreads();
#pragma unroll
        for (int k2 = 0; k2 < 2; ++k2) {
            int kc = p * 2 + k2;
            short8 afh, afl;
            if (MODE == 0) {
                const float* ap = &Af[(size_t)arow * K + kc * 32 + quad * 8];
                float4 a0 = *reinterpret_cast<const float4*>(ap);
                float4 a1 = *reinterpret_cast<const float4*>(ap + 4);
                cvt_hilo8(a0, a1, afh, afl);
            } else {
                size_t ao = (size_t)arow * K + kc * 32 + quad * 8;
                afh = *reinterpret_cast<const short8*>(&Ahg[ao]);
                afl = *reinterpret_cast<const short8*>(&Alg[ao]);
            }
            const unsigned short* wb = &WS[k2 * 8192 + lane * 8];
#pragma unroll
            for (int nt = 0; nt < 8; ++nt) {
                short8 bfh = *reinterpret_cast<const short8*>(wb + nt * 512);
                short8 bfl = *reinterpret_cast<const short8*>(wb + 4096 + nt * 512);
                acc[nt] = __builtin_amdgcn_mfma_f32_16x16x32_bf16(afh, bfh, acc[nt], 0, 0, 0);
                acc[nt] = __builtin_amdgcn_mfma_f32_16x16x32_bf16(afl, bfh, acc[nt], 0, 0, 0);
                acc[nt] = __builtin_amdgcn_mfma_f32_16x16x32_bf16(afh, bfl, acc[nt], 0, 0, 0);
            }
        }
    }

    float cb[8], rt[8], gm[8], bt[8];
#pragma unroll
    for (int nt = 0; nt < 8; ++nt) {
        int colh = nt * 16 + lrow;
        cb[nt] = bias[colh];
        if (MODE >= 1) rt[nt] = root[colh];
        if (MODE == 1) { gm[nt] = gamma[colh]; bt[nt] = beta[colh]; }
    }

#pragma unroll
    for (int r = 0; r < 4; ++r) {
        int grow = bm + wave * 16 + quad * 4 + r;
        bool ok = (grow < M);
        int gr = ok ? grow : M - 1;
        float x[8];
        if (MODE == 0) {
#pragma unroll
            for (int nt = 0; nt < 8; ++nt) x[nt] = acc[nt][r] + cb[nt];
        } else {
            float di = deg_inv[gr];
            float hv[8];
#pragma unroll
            for (int nt = 0; nt < 8; ++nt) hv[nt] = h[(size_t)gr * HF + nt * 16 + lrow];
#pragma unroll
            for (int nt = 0; nt < 8; ++nt) {
                float v = acc[nt][r] + cb[nt] + fmaxf(hv[nt] + rt[nt], 0.f) * di;
                x[nt] = (MODE == 1) ? v + hv[nt] : v;
            }
        }
        if (MODE == 1) {
            float s = 0.f;
#pragma unroll
            for (int nt = 0; nt < 8; ++nt) s += x[nt];
#pragma unroll
            for (int m = 1; m < 16; m <<= 1) s += __shfl_xor(s, m, 64);
            float mu = s * (1.0f / HF);
            float var = 0.f;
#pragma unroll
            for (int nt = 0; nt < 8; ++nt) { float d = x[nt] - mu; var += d * d; }
#pragma unroll
            for (int m = 1; m < 16; m <<= 1) var += __shfl_xor(var, m, 64);
            float rs = rsqrtf(var * (1.0f / HF) + 1e-5f);
            float ds = dis[gr];
            if (ok) {
#pragma unroll
                for (int nt = 0; nt < 8; ++nt) {
                    int colh = nt * 16 + lrow;
                    float y = fmaxf((x[nt] - mu) * rs * gm[nt] + bt[nt], 0.f);
                    C[(size_t)grow * HF + colh] = y;
                    Cbf[(size_t)grow * HF + colh] = f32_to_bf16_rne(ds * y);
                }
            }
        } else if (MODE == 0) {
            if (ok) {
                float ds = dis[grow];
#pragma unroll
                for (int nt = 0; nt < 8; ++nt) {
                    int colh = nt * 16 + lrow;
                    C[(size_t)grow * HF + colh] = x[nt];
                    Cbf[(size_t)grow * HF + colh] = f32_to_bf16_rne(ds * x[nt]);
                }
            }
        } else {
            if (ok) {
#pragma unroll
                for (int nt = 0; nt < 8; ++nt)
                    C[(size_t)grow * HF + nt * 16 + lrow] = x[nt];
            }
        }
    }
}

// ---------------- aggregate: agg = dis[t]*sum_e hbf[c] + deg_inv[t]*h[t] ----------------
// hbf pre-scaled by dis[c]; one wave per node. FAST PATH deg<=16 (~90% of nodes,
// Poisson(12)): each quarter issues its up-to-4 edge gathers as independent predicated
// loads -> 16 outstanding 16B gathers per wave, no serialized chain. Slow path: loop.
__global__ void aggregate(const int* __restrict__ row_start, const int* __restrict__ csr_col,
                          const float* __restrict__ dis, const float* __restrict__ deg_inv,
                          const float* __restrict__ h, const unsigned short* __restrict__ hbf,
                          unsigned short* __restrict__ agg_hi, unsigned short* __restrict__ agg_lo,
                          int n) {
    int wid = (blockIdx.x * blockDim.x + threadIdx.x) >> 6;
    int lane = threadIdx.x & 63;
    if (wid >= n) return;
    int q = lane >> 4;
    int l16 = lane & 15;
    int s = row_start[wid];
    int e = row_start[wid + 1];
    float a0 = 0.f, a1 = 0.f, a2 = 0.f, a3 = 0.f, a4 = 0.f, a5 = 0.f, a6 = 0.f, a7 = 0.f;
    if (e - s <= 16) {
        // quarter q covers edges s+q, s+q+4, s+q+8, s+q+12 (predicated)
        int j0 = s + q;
        bool p0 = j0 < e, p1 = j0 + 4 < e, p2 = j0 + 8 < e, p3 = j0 + 12 < e;
        int c0 = p0 ? csr_col[j0] : 0;
        int c1 = p1 ? csr_col[j0 + 4] : 0;
        int c2 = p2 ? csr_col[j0 + 8] : 0;
        int c3 = p3 ? csr_col[j0 + 12] : 0;
        uint4 z = make_uint4(0, 0, 0, 0);
        uint4 g0 = z, g1 = z, g2 = z, g3 = z;
        if (p0) g0 = *reinterpret_cast<const uint4*>(&hbf[(size_t)c0 * HF + l16 * 8]);
        if (p1) g1 = *reinterpret_cast<const uint4*>(&hbf[(size_t)c1 * HF + l16 * 8]);
        if (p2) g2 = *reinterpret_cast<const uint4*>(&hbf[(size_t)c2 * HF + l16 * 8]);
        if (p3) g3 = *reinterpret_cast<const uint4*>(&hbf[(size_t)c3 * HF + l16 * 8]);
        a0 = bf16lo_u32(g0.x) + bf16lo_u32(g1.x) + bf16lo_u32(g2.x) + bf16lo_u32(g3.x);
        a1 = bf16hi_u32(g0.x) + bf16hi_u32(g1.x) + bf16hi_u32(g2.x) + bf16hi_u32(g3.x);
        a2 = bf16lo_u32(g0.y) + bf16lo_u32(g1.y) + bf16lo_u32(g2.y) + bf16lo_u32(g3.y);
        a3 = bf16hi_u32(g0.y) + bf16hi_u32(g1.y) + bf16hi_u32(g2.y) + bf16hi_u32(g3.y);
        a4 = bf16lo_u32(g0.z) + bf16lo_u32(g1.z) + bf16lo_u32(g2.z) + bf16lo_u32(g3.z);
        a5 = bf16hi_u32(g0.z) + bf16hi_u32(g1.z) + bf16hi_u32(g2.z) + bf16hi_u32(g3.z);
        a6 = bf16lo_u32(g0.w) + bf16lo_u32(g1.w) + bf16lo_u32(g2.w) + bf16lo_u32(g3.w);
        a7 = bf16hi_u32(g0.w) + bf16hi_u32(g1.w) + bf16hi_u32(g2.w) + bf16hi_u32(g3.w);
    } else {
        float b0 = 0.f, b1 = 0.f, b2 = 0.f, b3 = 0.f, b4 = 0.f, b5 = 0.f, b6 = 0.f, b7 = 0.f;
        int j = s + q;
        for (; j + 4 < e; j += 8) {
            int c0 = csr_col[j];
            int c1 = csr_col[j + 4];
            uint4 h0 = *reinterpret_cast<const uint4*>(&hbf[(size_t)c0 * HF + l16 * 8]);
            uint4 h1 = *reinterpret_cast<const uint4*>(&hbf[(size_t)c1 * HF + l16 * 8]);
            a0 += bf16lo_u32(h0.x); a1 += bf16hi_u32(h0.x);
            a2 += bf16lo_u32(h0.y); a3 += bf16hi_u32(h0.y);
            a4 += bf16lo_u32(h0.z); a5 += bf16hi_u32(h0.z);
            a6 += bf16lo_u32(h0.w); a7 += bf16hi_u32(h0.w);
            b0 += bf16lo_u32(h1.x); b1 += bf16hi_u32(h1.x);
            b2 += bf16lo_u32(h1.y); b3 += bf16hi_u32(h1.y);
            b4 += bf16lo_u32(h1.z); b5 += bf16hi_u32(h1.z);
            b6 += bf16lo_u32(h1.w); b7 += bf16hi_u32(h1.w);
        }
        if (j < e) {
            int c0 = csr_col[j];
            uint4 h0 = *reinterpret_cast<const uint4*>(&hbf[(size_t)c0 * HF + l16 * 8]);
            a0 += bf16lo_u32(h0.x); a1 += bf16hi_u32(h0.x);
            a2 += bf16lo_u32(h0.y); a3 += bf16hi_u32(h0.y);
            a4 += bf16lo_u32(h0.z); a5 += bf16hi_u32(h0.z);
            a6 += bf16lo_u32(h0.w); a7 += bf16hi_u32(h0.w);
        }
        a0 += b0; a1 += b1; a2 += b2; a3 += b3;
        a4 += b4; a5 += b5; a6 += b6; a7 += b7;
    }
#pragma unroll
    for (int m = 16; m < 64; m <<= 1) {
        a0 += __shfl_xor(a0, m, 64);
        a1 += __shfl_xor(a1, m, 64);
        a2 += __shfl_xor(a2, m, 64);
        a3 += __shfl_xor(a3, m, 64);
        a4 += __shfl_xor(a4, m, 64);
        a5 += __shfl_xor(a5, m, 64);
        a6 += __shfl_xor(a6, m, 64);
        a7 += __shfl_xor(a7, m, 64);
    }
    if (q == 0) {
        float dn = dis[wid];
        float di = deg_inv[wid];
        float4 hA = *reinterpret_cast<const float4*>(&h[(size_t)wid * HF + l16 * 8]);
        float4 hB = *reinterpret_cast<const float4*>(&h[(size_t)wid * HF + l16 * 8 + 4]);
        float o[8];
        o[0] = fmaf(dn, a0, di * hA.x);
        o[1] = fmaf(dn, a1, di * hA.y);
        o[2] = fmaf(dn, a2, di * hA.z);
        o[3] = fmaf(dn, a3, di * hA.w);
        o[4] = fmaf(dn, a4, di * hB.x);
        o[5] = fmaf(dn, a5, di * hB.y);
        o[6] = fmaf(dn, a6, di * hB.z);
        o[7] = fmaf(dn, a7, di * hB.w);
        unsigned short hi[8], lo[8];
#pragma unroll
        for (int k = 0; k < 8; ++k) {
            hi[k] = f32_to_bf16_rne(o[k]);
            lo[k] = f32_to_bf16_rne(o[k] - bf16_to_f32(hi[k]));
        }
        uint4 hp, lp;
        hp.x = (unsigned)hi[0] | ((unsigned)hi[1] << 16);
        hp.y = (unsigned)hi[2] | ((unsigned)hi[3] << 16);
        hp.z = (unsigned)hi[4] | ((unsigned)hi[5] << 16);
        hp.w = (unsigned)hi[6] | ((unsigned)hi[7] << 16);
        lp.x = (unsigned)lo[0] | ((unsigned)lo[1] << 16);
        lp.y = (unsigned)lo[2] | ((unsigned)lo[3] << 16);
        lp.z = (unsigned)lo[4] | ((unsigned)lo[5] << 16);
        lp.w = (unsigned)lo[6] | ((unsigned)lo[7] << 16);
        *reinterpret_cast<uint4*>(&agg_hi[(size_t)wid * HF + l16 * 8]) = hp;
        *reinterpret_cast<uint4*>(&agg_lo[(size_t)wid * HF + l16 * 8]) = lp;
    }
}

extern "C" void kernel_launch(void* const* d_in, const int* in_sizes, int n_in,
                              void* d_out, int out_size, void* d_ws, size_t ws_size,
                              hipStream_t stream) {
    const int N = NN, E = EE;
    const float* in_feat = (const float*)d_in[0];
    const int* row = (const int*)d_in[1];
    const int* col = (const int*)d_in[2];
    const float* lin_w = (const float*)d_in[3];
    const float* lin_b = (const float*)d_in[4];
    const float* conv_w = (const float*)d_in[5];
    const float* conv_b = (const float*)d_in[6];
    const float* root_emb = (const float*)d_in[7];
    const float* ln_gamma = (const float*)d_in[8];
    const float* ln_beta = (const float*)d_in[9];
    float* out = (float*)d_out;

    // workspace layout (4B units); all segments kept 16B-aligned
    float* ws = (float*)d_ws;
    size_t o = 0;
    float* deg_inv = ws + o; o += N;
    float* dis = ws + o; o += N;
    int* cnt = (int*)(ws + o); o += N;
    int* row_start = (int*)(ws + o); o += N + 4;
    int* fill_pos = (int*)(ws + o); o += N;
    int* bsum = (int*)(ws + o); o += 256;
    int* csr_col = (int*)(ws + o); o += E;
    o = (o + 3) & ~(size_t)3;
    unsigned short* fl = (unsigned short*)(ws + o); o += 32768;  // 65536 ushort (128KB)
    unsigned short* fc = (unsigned short*)(ws + o); o += 16384;  // 32768 ushort (64KB)
    float* h0 = ws + o; o += (size_t)N * HF;
    unsigned short* hbf = (unsigned short*)(ws + o); o += (size_t)N * HF / 2;
    unsigned short* agg_hi = (unsigned short*)(ws + o); o += (size_t)N * HF / 2;
    unsigned short* agg_lo = (unsigned short*)(ws + o); o += (size_t)N * HF / 2;

    const int NB = (N + 255) / 256;   // 196

    hipMemsetAsync(cnt, 0, N * sizeof(int), stream);
    count_and_prepack<<<CEB + 48, 256, 0, stream>>>(row, cnt, E, lin_w, conv_w, fl, fc);
    scan_phase1<<<NB, 256, 0, stream>>>(cnt, bsum, N);
    scan_phase3<<<NB, 256, 0, stream>>>(cnt, bsum, row_start, fill_pos, deg_inv, dis, N, NB, E);
    fill_csr<<<CEB, 256, 0, stream>>>(row, col, fill_pos, csr_col, E);

    const int GB = (N + 63) / 64;
    const int WB = (N + 3) / 4;

    // h0 = in_feat @ lin_w.T + lin_b  (f32 + dis-scaled bf16 copy)
    gemm_ldsw<INF, 0><<<GB, 256, 0, stream>>>(in_feat, nullptr, nullptr, fl, lin_b,
                                              h0, hbf, nullptr, nullptr, dis, nullptr,
                                              nullptr, nullptr, N);

    // ---- prop step 0 (conv + fused residual/LN/ReLU epilogue -> h0 in-place) ----
    aggregate<<<WB, 256, 0, stream>>>(row_start, csr_col, dis, deg_inv, h0, hbf,
                                      agg_hi, agg_lo, N);
    gemm_ldsw<HF, 1><<<GB, 256, 0, stream>>>(nullptr, agg_hi, agg_lo, fc, conv_b,
                                             h0, hbf, h0, deg_inv, dis, root_emb,
                                             ln_gamma + HF, ln_beta + HF, N);

    // ---- prop step 1 (conv + combine epilogue -> out) ----
    aggregate<<<WB, 256, 0, stream>>>(row_start, csr_col, dis, deg_inv, h0, hbf,
                                      agg_hi, agg_lo, N);
    gemm_ldsw<HF, 2><<<GB, 256, 0, stream>>>(nullptr, agg_hi, agg_lo, fc, conv_b,
                                             out, nullptr, h0, deg_inv, dis, root_emb,
                                             nullptr, nullptr, N);
}

// Round 9
// 292.602 us; speedup vs baseline: 1.1332x; 1.0631x over previous
//
#include <hip/hip_runtime.h>

#define NN 50000
#define EE 600000
#define INF 256
#define HF 128
#define CEB ((EE + 255) / 256)   // 2344 blocks for edge-parallel work

typedef __attribute__((ext_vector_type(8))) short short8;
typedef __attribute__((ext_vector_type(4))) float floatx4;

// ---------------- bf16 helpers ----------------
__device__ __forceinline__ unsigned short f32_to_bf16_rne(float x) {
    unsigned int u = __float_as_uint(x);
    unsigned int r = (u + 0x7FFFu + ((u >> 16) & 1u)) >> 16;
    return (unsigned short)r;
}
__device__ __forceinline__ float bf16_to_f32(unsigned short h) {
    return __uint_as_float(((unsigned int)h) << 16);
}
__device__ __forceinline__ float bf16lo_u32(unsigned int u) {
    return __uint_as_float(u << 16);
}
__device__ __forceinline__ float bf16hi_u32(unsigned int u) {
    return __uint_as_float(u & 0xFFFF0000u);
}
// 8 f32 -> hi/lo bf16 fragment pair
__device__ __forceinline__ void cvt_hilo8(float4 v0, float4 v1, short8& hs, short8& ls) {
    float x[8] = {v0.x, v0.y, v0.z, v0.w, v1.x, v1.y, v1.z, v1.w};
    union { short8 s; unsigned short u[8]; } H, L;
#pragma unroll
    for (int k = 0; k < 8; ++k) {
        unsigned short hi = f32_to_bf16_rne(x[k]);
        H.u[k] = hi;
        L.u[k] = f32_to_bf16_rne(x[k] - bf16_to_f32(hi));
    }
    hs = H.s;
    ls = L.s;
}

// ---------------- fused: degree counting (saving per-edge rank) + weight prepack -------
// pos[e] = this edge's rank within its target node -> fill_csr needs no atomics.
__global__ void count_and_prepack(const int* __restrict__ row, int* __restrict__ cnt,
                                  int* __restrict__ pos, int E,
                                  const float* __restrict__ lw, const float* __restrict__ cw,
                                  unsigned short* __restrict__ fl, unsigned short* __restrict__ fc) {
    int b = blockIdx.x;
    if (b < CEB) {
        int e = b * 256 + threadIdx.x;
        if (e < E) pos[e] = atomicAdd(&cnt[row[e]], 1);
        return;
    }
    int idx = (b - CEB) * 256 + threadIdx.x;
    const float* src;
    unsigned short* dst;
    int K, c;
    if (idx < 8192) {
        src = lw; dst = fl; K = INF; c = idx;
    } else if (idx < 12288) {
        src = cw; dst = fc; K = HF; c = idx - 8192;
    } else return;
    int lane = c & 63;
    int nt = (c >> 6) & 7;
    int hl = (c >> 9) & 1;
    int kc = c >> 10;
    int rw = nt * 16 + (lane & 15);
    int koff = kc * 32 + (lane >> 4) * 8;
    const float* p = &src[(size_t)rw * K + koff];
    float4 v0 = *reinterpret_cast<const float4*>(p);
    float4 v1 = *reinterpret_cast<const float4*>(p + 4);
    short8 hs, ls;
    cvt_hilo8(v0, v1, hs, ls);
    *reinterpret_cast<short8*>(&dst[(size_t)c * 8]) = hl ? ls : hs;
}

// ---------------- scan phase1: per-block sums of cnt ----------------
__global__ void scan_phase1(const int* __restrict__ cnt, int* __restrict__ bsum, int n) {
    __shared__ int sdata[256];
    int t = threadIdx.x;
    int i = blockIdx.x * 256 + t;
    sdata[t] = (i < n) ? cnt[i] : 0;
    __syncthreads();
    for (int s = 128; s > 0; s >>= 1) {
        if (t < s) sdata[t] += sdata[t + s];
        __syncthreads();
    }
    if (t == 0) bsum[blockIdx.x] = sdata[0];
}

// ---------------- scan phase2+3 fused (+ finalize_deg): every block re-scans bsum ------
__global__ void scan_phase3(const int* __restrict__ cnt, const int* __restrict__ bsum,
                            int* __restrict__ row_start,
                            float* __restrict__ deg_inv, float* __restrict__ dis,
                            int n, int nb, int E) {
    __shared__ int sb[256];
    __shared__ int sdata[256];
    int t = threadIdx.x;
    sb[t] = (t < nb) ? bsum[t] : 0;
    __syncthreads();
    for (int s = 1; s < 256; s <<= 1) {
        int add = (t >= s) ? sb[t - s] : 0;
        __syncthreads();
        sb[t] += add;
        __syncthreads();
    }
    int base = sb[blockIdx.x] - bsum[blockIdx.x];
    int i = blockIdx.x * 256 + t;
    int v = (i < n) ? cnt[i] : 0;
    sdata[t] = v;
    __syncthreads();
    for (int s = 1; s < 256; s <<= 1) {
        int add = (t >= s) ? sdata[t - s] : 0;
        __syncthreads();
        sdata[t] += add;
        __syncthreads();
    }
    if (i < n) {
        int ex = base + sdata[t] - v;
        row_start[i] = ex;
        float d = (float)(v + 1);
        deg_inv[i] = 1.0f / d;
        dis[i] = rsqrtf(d);
    }
    if (blockIdx.x == 0 && t == 0) row_start[n] = E;
}

// atomic-free: p = row_start[row[e]] + pos[e]; scattered nt store of col
__global__ void fill_csr(const int* __restrict__ row, const int* __restrict__ col,
                         const int* __restrict__ row_start, const int* __restrict__ pos,
                         int* __restrict__ csr_col, int E) {
    int e = blockIdx.x * blockDim.x + threadIdx.x;
    if (e < E) {
        int p = row_start[row[e]] + pos[e];
        __builtin_nontemporal_store(col[e], &csr_col[p]);
    }
}

// ---------------- split-bf16 MFMA GEMM, W staged in LDS in 32KB chunks ----------------
template <int K, int MODE>
__global__ __launch_bounds__(256) void gemm_ldsw(
    const float* __restrict__ Af,
    const unsigned short* __restrict__ Ahg, const unsigned short* __restrict__ Alg,
    const unsigned short* __restrict__ Wf,
    const float* __restrict__ bias,
    float* __restrict__ C, unsigned short* __restrict__ Cbf,
    const float* __restrict__ h, const float* __restrict__ deg_inv,
    const float* __restrict__ dis, const float* __restrict__ root,
    const float* __restrict__ gamma, const float* __restrict__ beta,
    int M) {
    constexpr int NKC = K / 32;
    __shared__ unsigned short WS[2 * 8192];   // 2 kc x 16KB = 32KB

    const int t = threadIdx.x;
    const int wave = t >> 6;
    const int lane = t & 63;
    const int lrow = lane & 15;
    const int quad = lane >> 4;
    const int bm = blockIdx.x * 64;
    int arow = bm + wave * 16 + lrow;
    if (arow >= M) arow = M - 1;   // clamp; stores are predicated

    floatx4 acc[8];
#pragma unroll
    for (int nt = 0; nt < 8; ++nt) acc[nt] = (floatx4){0.f, 0.f, 0.f, 0.f};

#pragma unroll
    for (int p = 0; p < NKC / 2; ++p) {
        if (p) __syncthreads();
        {
            const uint4* src = reinterpret_cast<const uint4*>(Wf + (size_t)p * 16384);
            uint4* dstl = reinterpret_cast<uint4*>(WS);
#pragma unroll
            for (int i = 0; i < 8; ++i) dstl[t + 256 * i] = src[t + 256 * i];
        }
        __syncthreads();
#pragma unroll
        for (int k2 = 0; k2 < 2; ++k2) {
            int kc = p * 2 + k2;
            short8 afh, afl;
            if (MODE == 0) {
                const float* ap = &Af[(size_t)arow * K + kc * 32 + quad * 8];
                float4 a0 = *reinterpret_cast<const float4*>(ap);
                float4 a1 = *reinterpret_cast<const float4*>(ap + 4);
                cvt_hilo8(a0, a1, afh, afl);
            } else {
                size_t ao = (size_t)arow * K + kc * 32 + quad * 8;
                afh = *reinterpret_cast<const short8*>(&Ahg[ao]);
                afl = *reinterpret_cast<const short8*>(&Alg[ao]);
            }
            const unsigned short* wb = &WS[k2 * 8192 + lane * 8];
#pragma unroll
            for (int nt = 0; nt < 8; ++nt) {
                short8 bfh = *reinterpret_cast<const short8*>(wb + nt * 512);
                short8 bfl = *reinterpret_cast<const short8*>(wb + 4096 + nt * 512);
                acc[nt] = __builtin_amdgcn_mfma_f32_16x16x32_bf16(afh, bfh, acc[nt], 0, 0, 0);
                acc[nt] = __builtin_amdgcn_mfma_f32_16x16x32_bf16(afl, bfh, acc[nt], 0, 0, 0);
                acc[nt] = __builtin_amdgcn_mfma_f32_16x16x32_bf16(afh, bfl, acc[nt], 0, 0, 0);
            }
        }
    }

    float cb[8], rt[8], gm[8], bt[8];
#pragma unroll
    for (int nt = 0; nt < 8; ++nt) {
        int colh = nt * 16 + lrow;
        cb[nt] = bias[colh];
        if (MODE >= 1) rt[nt] = root[colh];
        if (MODE == 1) { gm[nt] = gamma[colh]; bt[nt] = beta[colh]; }
    }

#pragma unroll
    for (int r = 0; r < 4; ++r) {
        int grow = bm + wave * 16 + quad * 4 + r;
        bool ok = (grow < M);
        int gr = ok ? grow : M - 1;
        float x[8];
        if (MODE == 0) {
#pragma unroll
            for (int nt = 0; nt < 8; ++nt) x[nt] = acc[nt][r] + cb[nt];
        } else {
            float di = deg_inv[gr];
            float hv[8];
#pragma unroll
            for (int nt = 0; nt < 8; ++nt) hv[nt] = h[(size_t)gr * HF + nt * 16 + lrow];
#pragma unroll
            for (int nt = 0; nt < 8; ++nt) {
                float v = acc[nt][r] + cb[nt] + fmaxf(hv[nt] + rt[nt], 0.f) * di;
                x[nt] = (MODE == 1) ? v + hv[nt] : v;
            }
        }
        if (MODE == 1) {
            float s = 0.f;
#pragma unroll
            for (int nt = 0; nt < 8; ++nt) s += x[nt];
#pragma unroll
            for (int m = 1; m < 16; m <<= 1) s += __shfl_xor(s, m, 64);
            float mu = s * (1.0f / HF);
            float var = 0.f;
#pragma unroll
            for (int nt = 0; nt < 8; ++nt) { float d = x[nt] - mu; var += d * d; }
#pragma unroll
            for (int m = 1; m < 16; m <<= 1) var += __shfl_xor(var, m, 64);
            float rs = rsqrtf(var * (1.0f / HF) + 1e-5f);
            float ds = dis[gr];
            if (ok) {
#pragma unroll
                for (int nt = 0; nt < 8; ++nt) {
                    int colh = nt * 16 + lrow;
                    float y = fmaxf((x[nt] - mu) * rs * gm[nt] + bt[nt], 0.f);
                    C[(size_t)grow * HF + colh] = y;
                    Cbf[(size_t)grow * HF + colh] = f32_to_bf16_rne(ds * y);
                }
            }
        } else if (MODE == 0) {
            if (ok) {
                float ds = dis[grow];
#pragma unroll
                for (int nt = 0; nt < 8; ++nt) {
                    int colh = nt * 16 + lrow;
                    C[(size_t)grow * HF + colh] = x[nt];
                    Cbf[(size_t)grow * HF + colh] = f32_to_bf16_rne(ds * x[nt]);
                }
            }
        } else {
            if (ok) {
#pragma unroll
                for (int nt = 0; nt < 8; ++nt)
                    C[(size_t)grow * HF + nt * 16 + lrow] = x[nt];
            }
        }
    }
}

// ---------------- aggregate: agg = dis[t]*sum_e hbf[c] + deg_inv[t]*h[t] ----------------
__global__ void aggregate(const int* __restrict__ row_start, const int* __restrict__ csr_col,
                          const float* __restrict__ dis, const float* __restrict__ deg_inv,
                          const float* __restrict__ h, const unsigned short* __restrict__ hbf,
                          unsigned short* __restrict__ agg_hi, unsigned short* __restrict__ agg_lo,
                          int n) {
    int wid = (blockIdx.x * blockDim.x + threadIdx.x) >> 6;
    int lane = threadIdx.x & 63;
    if (wid >= n) return;
    int q = lane >> 4;
    int l16 = lane & 15;
    int s = row_start[wid];
    int e = row_start[wid + 1];
    float a0 = 0.f, a1 = 0.f, a2 = 0.f, a3 = 0.f, a4 = 0.f, a5 = 0.f, a6 = 0.f, a7 = 0.f;
    if (e - s <= 16) {
        int j0 = s + q;
        bool p0 = j0 < e, p1 = j0 + 4 < e, p2 = j0 + 8 < e, p3 = j0 + 12 < e;
        int c0 = p0 ? csr_col[j0] : 0;
        int c1 = p1 ? csr_col[j0 + 4] : 0;
        int c2 = p2 ? csr_col[j0 + 8] : 0;
        int c3 = p3 ? csr_col[j0 + 12] : 0;
        uint4 z = make_uint4(0, 0, 0, 0);
        uint4 g0 = z, g1 = z, g2 = z, g3 = z;
        if (p0) g0 = *reinterpret_cast<const uint4*>(&hbf[(size_t)c0 * HF + l16 * 8]);
        if (p1) g1 = *reinterpret_cast<const uint4*>(&hbf[(size_t)c1 * HF + l16 * 8]);
        if (p2) g2 = *reinterpret_cast<const uint4*>(&hbf[(size_t)c2 * HF + l16 * 8]);
        if (p3) g3 = *reinterpret_cast<const uint4*>(&hbf[(size_t)c3 * HF + l16 * 8]);
        a0 = bf16lo_u32(g0.x) + bf16lo_u32(g1.x) + bf16lo_u32(g2.x) + bf16lo_u32(g3.x);
        a1 = bf16hi_u32(g0.x) + bf16hi_u32(g1.x) + bf16hi_u32(g2.x) + bf16hi_u32(g3.x);
        a2 = bf16lo_u32(g0.y) + bf16lo_u32(g1.y) + bf16lo_u32(g2.y) + bf16lo_u32(g3.y);
        a3 = bf16hi_u32(g0.y) + bf16hi_u32(g1.y) + bf16hi_u32(g2.y) + bf16hi_u32(g3.y);
        a4 = bf16lo_u32(g0.z) + bf16lo_u32(g1.z) + bf16lo_u32(g2.z) + bf16lo_u32(g3.z);
        a5 = bf16hi_u32(g0.z) + bf16hi_u32(g1.z) + bf16hi_u32(g2.z) + bf16hi_u32(g3.z);
        a6 = bf16lo_u32(g0.w) + bf16lo_u32(g1.w) + bf16lo_u32(g2.w) + bf16lo_u32(g3.w);
        a7 = bf16hi_u32(g0.w) + bf16hi_u32(g1.w) + bf16hi_u32(g2.w) + bf16hi_u32(g3.w);
    } else {
        float b0 = 0.f, b1 = 0.f, b2 = 0.f, b3 = 0.f, b4 = 0.f, b5 = 0.f, b6 = 0.f, b7 = 0.f;
        int j = s + q;
        for (; j + 4 < e; j += 8) {
            int c0 = csr_col[j];
            int c1 = csr_col[j + 4];
            uint4 h0 = *reinterpret_cast<const uint4*>(&hbf[(size_t)c0 * HF + l16 * 8]);
            uint4 h1 = *reinterpret_cast<const uint4*>(&hbf[(size_t)c1 * HF + l16 * 8]);
            a0 += bf16lo_u32(h0.x); a1 += bf16hi_u32(h0.x);
            a2 += bf16lo_u32(h0.y); a3 += bf16hi_u32(h0.y);
            a4 += bf16lo_u32(h0.z); a5 += bf16hi_u32(h0.z);
            a6 += bf16lo_u32(h0.w); a7 += bf16hi_u32(h0.w);
            b0 += bf16lo_u32(h1.x); b1 += bf16hi_u32(h1.x);
            b2 += bf16lo_u32(h1.y); b3 += bf16hi_u32(h1.y);
            b4 += bf16lo_u32(h1.z); b5 += bf16hi_u32(h1.z);
            b6 += bf16lo_u32(h1.w); b7 += bf16hi_u32(h1.w);
        }
        if (j < e) {
            int c0 = csr_col[j];
            uint4 h0 = *reinterpret_cast<const uint4*>(&hbf[(size_t)c0 * HF + l16 * 8]);
            a0 += bf16lo_u32(h0.x); a1 += bf16hi_u32(h0.x);
            a2 += bf16lo_u32(h0.y); a3 += bf16hi_u32(h0.y);
            a4 += bf16lo_u32(h0.z); a5 += bf16hi_u32(h0.z);
            a6 += bf16lo_u32(h0.w); a7 += bf16hi_u32(h0.w);
        }
        a0 += b0; a1 += b1; a2 += b2; a3 += b3;
        a4 += b4; a5 += b5; a6 += b6; a7 += b7;
    }
#pragma unroll
    for (int m = 16; m < 64; m <<= 1) {
        a0 += __shfl_xor(a0, m, 64);
        a1 += __shfl_xor(a1, m, 64);
        a2 += __shfl_xor(a2, m, 64);
        a3 += __shfl_xor(a3, m, 64);
        a4 += __shfl_xor(a4, m, 64);
        a5 += __shfl_xor(a5, m, 64);
        a6 += __shfl_xor(a6, m, 64);
        a7 += __shfl_xor(a7, m, 64);
    }
    if (q == 0) {
        float dn = dis[wid];
        float di = deg_inv[wid];
        float4 hA = *reinterpret_cast<const float4*>(&h[(size_t)wid * HF + l16 * 8]);
        float4 hB = *reinterpret_cast<const float4*>(&h[(size_t)wid * HF + l16 * 8 + 4]);
        float o[8];
        o[0] = fmaf(dn, a0, di * hA.x);
        o[1] = fmaf(dn, a1, di * hA.y);
        o[2] = fmaf(dn, a2, di * hA.z);
        o[3] = fmaf(dn, a3, di * hA.w);
        o[4] = fmaf(dn, a4, di * hB.x);
        o[5] = fmaf(dn, a5, di * hB.y);
        o[6] = fmaf(dn, a6, di * hB.z);
        o[7] = fmaf(dn, a7, di * hB.w);
        unsigned short hi[8], lo[8];
#pragma unroll
        for (int k = 0; k < 8; ++k) {
            hi[k] = f32_to_bf16_rne(o[k]);
            lo[k] = f32_to_bf16_rne(o[k] - bf16_to_f32(hi[k]));
        }
        uint4 hp, lp;
        hp.x = (unsigned)hi[0] | ((unsigned)hi[1] << 16);
        hp.y = (unsigned)hi[2] | ((unsigned)hi[3] << 16);
        hp.z = (unsigned)hi[4] | ((unsigned)hi[5] << 16);
        hp.w = (unsigned)hi[6] | ((unsigned)hi[7] << 16);
        lp.x = (unsigned)lo[0] | ((unsigned)lo[1] << 16);
        lp.y = (unsigned)lo[2] | ((unsigned)lo[3] << 16);
        lp.z = (unsigned)lo[4] | ((unsigned)lo[5] << 16);
        lp.w = (unsigned)lo[6] | ((unsigned)lo[7] << 16);
        *reinterpret_cast<uint4*>(&agg_hi[(size_t)wid * HF + l16 * 8]) = hp;
        *reinterpret_cast<uint4*>(&agg_lo[(size_t)wid * HF + l16 * 8]) = lp;
    }
}

extern "C" void kernel_launch(void* const* d_in, const int* in_sizes, int n_in,
                              void* d_out, int out_size, void* d_ws, size_t ws_size,
                              hipStream_t stream) {
    const int N = NN, E = EE;
    const float* in_feat = (const float*)d_in[0];
    const int* row = (const int*)d_in[1];
    const int* col = (const int*)d_in[2];
    const float* lin_w = (const float*)d_in[3];
    const float* lin_b = (const float*)d_in[4];
    const float* conv_w = (const float*)d_in[5];
    const float* conv_b = (const float*)d_in[6];
    const float* root_emb = (const float*)d_in[7];
    const float* ln_gamma = (const float*)d_in[8];
    const float* ln_beta = (const float*)d_in[9];
    float* out = (float*)d_out;

    // workspace layout (4B units); all segments kept 16B-aligned
    float* ws = (float*)d_ws;
    size_t o = 0;
    float* deg_inv = ws + o; o += N;
    float* dis = ws + o; o += N;
    int* cnt = (int*)(ws + o); o += N;
    int* row_start = (int*)(ws + o); o += N + 4;
    int* pos = (int*)(ws + o); o += E;
    int* bsum = (int*)(ws + o); o += 256;
    int* csr_col = (int*)(ws + o); o += E;
    o = (o + 3) & ~(size_t)3;
    unsigned short* fl = (unsigned short*)(ws + o); o += 32768;  // 65536 ushort (128KB)
    unsigned short* fc = (unsigned short*)(ws + o); o += 16384;  // 32768 ushort (64KB)
    float* h0 = ws + o; o += (size_t)N * HF;
    unsigned short* hbf = (unsigned short*)(ws + o); o += (size_t)N * HF / 2;
    unsigned short* agg_hi = (unsigned short*)(ws + o); o += (size_t)N * HF / 2;
    unsigned short* agg_lo = (unsigned short*)(ws + o); o += (size_t)N * HF / 2;

    const int NB = (N + 255) / 256;   // 196

    hipMemsetAsync(cnt, 0, N * sizeof(int), stream);
    count_and_prepack<<<CEB + 48, 256, 0, stream>>>(row, cnt, pos, E, lin_w, conv_w, fl, fc);
    scan_phase1<<<NB, 256, 0, stream>>>(cnt, bsum, N);
    scan_phase3<<<NB, 256, 0, stream>>>(cnt, bsum, row_start, deg_inv, dis, N, NB, E);
    fill_csr<<<CEB, 256, 0, stream>>>(row, col, row_start, pos, csr_col, E);

    const int GB = (N + 63) / 64;
    const int WB = (N + 3) / 4;

    // h0 = in_feat @ lin_w.T + lin_b  (f32 + dis-scaled bf16 copy)
    gemm_ldsw<INF, 0><<<GB, 256, 0, stream>>>(in_feat, nullptr, nullptr, fl, lin_b,
                                              h0, hbf, nullptr, nullptr, dis, nullptr,
                                              nullptr, nullptr, N);

    // ---- prop step 0 (conv + fused residual/LN/ReLU epilogue -> h0 in-place) ----
    aggregate<<<WB, 256, 0, stream>>>(row_start, csr_col, dis, deg_inv, h0, hbf,
                                      agg_hi, agg_lo, N);
    gemm_ldsw<HF, 1><<<GB, 256, 0, stream>>>(nullptr, agg_hi, agg_lo, fc, conv_b,
                                             h0, hbf, h0, deg_inv, dis, root_emb,
                                             ln_gamma + HF, ln_beta + HF, N);

    // ---- prop step 1 (conv + combine epilogue -> out) ----
    aggregate<<<WB, 256, 0, stream>>>(row_start, csr_col, dis, deg_inv, h0, hbf,
                                      agg_hi, agg_lo, N);
    gemm_ldsw<HF, 2><<<GB, 256, 0, stream>>>(nullptr, agg_hi, agg_lo, fc, conv_b,
                                             out, nullptr, h0, deg_inv, dis, root_emb,
                                             nullptr, nullptr, N);
}